// Round 14
// baseline (1196.649 us; speedup 1.0000x reference)
//
#include <hip/hip_runtime.h>
#include <hip/hip_bf16.h>
#include <math.h>

#define EPS_ 1e-5f

typedef _Float16 half8_t __attribute__((ext_vector_type(8)));
typedef _Float16 half2_t __attribute__((ext_vector_type(2)));
typedef float f32x4_t __attribute__((ext_vector_type(4)));
typedef short bf16x8_t __attribute__((ext_vector_type(8)));

// fast GELU (tanh form), |err| vs exact erf-GELU <~4e-4; clamped for inf-safety
__device__ __forceinline__ float gelu_f(float x) {
  float u2 = x * fmaf(0.0713548162f, x * x, 1.5957691216f);
  u2 = fminf(u2, 80.f);
  float e = __expf(u2);
  return x - x / (1.f + e);
}

__device__ __forceinline__ float wred64(float v) {
#pragma unroll
  for (int m = 32; m > 0; m >>= 1) v += __shfl_xor(v, m, 64);
  return v;
}

// ---------------- K0: fp16 transposed DFT table tabT[s][t], s in [0,450) ----------------
__global__ void k_table(_Float16* __restrict__ tabT) {
  int idx = blockIdx.x * 256 + threadIdx.x;
  if (idx >= 450 * 1024) return;
  int s = idx >> 10;
  int t = idx & 1023;
  int f = (s < 225) ? (32 + s) : (s - 225 + 32);
  int ph = (f * t) & 1023;
  float ang = (float)ph * (6.2831853071795864769e0f / 1024.0f);
  float v = ((s < 225) ? cosf(ang) : -sinf(ang)) * (1.0f / 1024.0f);
  tabT[idx] = (_Float16)v;
}

// ---------------- K0b: pack conv + proj weights (fp16 fragments) + w1 bf16 copy ----------------
__global__ void k_prep(const float* __restrict__ cw0, const float* __restrict__ cw1,
                       const float* __restrict__ pw0, const float* __restrict__ pw1,
                       const float* __restrict__ w1,
                       _Float16* __restrict__ wf, _Float16* __restrict__ pwf,
                       __hip_bfloat16* __restrict__ w1b) {
  int idx = blockIdx.x * 256 + threadIdx.x;
  if (idx < 32768) {
    int j = idx & 7;
    int l = (idx >> 3) & 63;
    int t = (idx >> 9) & 15;
    int e = idx >> 13;
    int g = l >> 4, o = l & 15;
    int i = 8 * (g & 1) + j;
    int k = 2 * t + (g >> 1);
    const float* cw = e ? cw1 : cw0;
    float v = (k < 31) ? cw[(o * 16 + i) * 31 + k] : 0.f;
    wf[idx] = (_Float16)v;
  } else if (idx < 62464) {
    int idx2 = idx - 32768;
    int e = idx2 / 14848;
    int r = idx2 - e * 14848;
    int T = r >> 9;
    int l = (r >> 3) & 63;
    int j = r & 7;
    int g = l >> 4;
    int c = 8 * g + j;
    int s = 16 * T + (l & 15);
    const float* pws = e ? pw1 : pw0;
    float v = (c < 16 && s < 450) ? pws[s * 16 + c] : 0.f;
    pwf[idx2] = (_Float16)v;
  } else if (idx < 62464 + 518400) {
    int idx2 = idx - 62464;
    w1b[idx2] = __float2bfloat16(w1[idx2]);
  }
}

// ---------------- K1: DFT GEMM via fp16 MFMA, split x = hi + lo ----------------
__global__ __launch_bounds__(256) void k_dft(const float* __restrict__ X,
                                             const _Float16* __restrict__ tabT,
                                             float* __restrict__ C) {
  __shared__ _Float16 As[2][32][72];   // [hi/lo][m][k] pitch 72 halfs

  const int tid = threadIdx.x;
  const int l = tid & 63;
  const int w = tid >> 6;        // wave -> n-strip base 128*w
  const int g = l >> 4;
  const int n16 = l & 15;
  const int m0 = blockIdx.x * 32;

  const int sm = tid >> 3;          // staging row 0..31
  const int sk = (tid & 7) * 4;     // staging k 0..28

  f32x4_t acc[2][8];
#pragma unroll
  for (int fi = 0; fi < 2; fi++)
#pragma unroll
    for (int nj = 0; nj < 8; nj++) acc[fi][nj] = (f32x4_t){0.f, 0.f, 0.f, 0.f};

  const float* xrow = X + (size_t)(m0 + sm) * 1024 + sk;

  for (int k0 = 0; k0 < 1024; k0 += 64) {
    float4 xa = *(const float4*)(xrow + k0);
    float4 xb = *(const float4*)(xrow + k0 + 32);
    __syncthreads();
    {
      _Float16 ha[4], la[4], hb[4], lb[4];
      float va[4] = {xa.x, xa.y, xa.z, xa.w};
      float vb[4] = {xb.x, xb.y, xb.z, xb.w};
#pragma unroll
      for (int q = 0; q < 4; q++) {
        ha[q] = (_Float16)va[q];
        la[q] = (_Float16)(va[q] - (float)ha[q]);
        hb[q] = (_Float16)vb[q];
        lb[q] = (_Float16)(vb[q] - (float)hb[q]);
      }
      *(half2_t*)&As[0][sm][sk]      = *(half2_t*)&ha[0];
      *(half2_t*)&As[0][sm][sk + 2]  = *(half2_t*)&ha[2];
      *(half2_t*)&As[1][sm][sk]      = *(half2_t*)&la[0];
      *(half2_t*)&As[1][sm][sk + 2]  = *(half2_t*)&la[2];
      *(half2_t*)&As[0][sm][sk + 32] = *(half2_t*)&hb[0];
      *(half2_t*)&As[0][sm][sk + 34] = *(half2_t*)&hb[2];
      *(half2_t*)&As[1][sm][sk + 32] = *(half2_t*)&lb[0];
      *(half2_t*)&As[1][sm][sk + 34] = *(half2_t*)&lb[2];
    }
    __syncthreads();
#pragma unroll
    for (int ks = 0; ks < 2; ks++) {
      half8_t a_hi[2], a_lo[2];
#pragma unroll
      for (int fi = 0; fi < 2; fi++) {
        a_hi[fi] = *(const half8_t*)&As[0][16 * fi + n16][ks * 32 + 8 * g];
        a_lo[fi] = *(const half8_t*)&As[1][16 * fi + n16][ks * 32 + 8 * g];
      }
#pragma unroll
      for (int nj = 0; nj < 8; nj++) {
        int s = 128 * w + 16 * nj + n16;
        int sc = (s < 450) ? s : 449;
        half8_t bf = *(const half8_t*)(tabT + (size_t)sc * 1024 + k0 + ks * 32 + 8 * g);
#pragma unroll
        for (int fi = 0; fi < 2; fi++) {
          acc[fi][nj] = __builtin_amdgcn_mfma_f32_16x16x32_f16(a_hi[fi], bf, acc[fi][nj], 0, 0, 0);
          acc[fi][nj] = __builtin_amdgcn_mfma_f32_16x16x32_f16(a_lo[fi], bf, acc[fi][nj], 0, 0, 0);
        }
      }
    }
  }

#pragma unroll
  for (int fi = 0; fi < 2; fi++)
#pragma unroll
    for (int nj = 0; nj < 8; nj++) {
      int s = 128 * w + 16 * nj + n16;
      if (s < 450) {
#pragma unroll
        for (int q = 0; q < 4; q++) {
          int m = m0 + 16 * fi + 4 * g + q;
          C[(size_t)m * 450 + s] = acc[fi][nj][q];
        }
      }
    }
}

// ---------------- K2: fused network, 256 thr / 4 waves, fp16 residual in LDS, 5 blk/CU ----------------
struct NetArgs {
  const float *ccw, *ccb, *cclnw, *cclnb;
  const float *l1w[2], *l1b[2], *l2w[2], *l2b[2], *l3w[2], *l3b[2];
  const float *cb[2], *pb[2];
  const _Float16* wf;    // [2][16][64][8] conv A-fragments (global, L1-hot)
  const _Float16* pwf;   // [2][29][64][8] proj B-fragments
  char* rec;
};

__global__ __launch_bounds__(256, 5) void k_net(NetArgs a) {
  __shared__ _Float16 h_s[16][452];              // 14464 B (residual stream, fp16)
  __shared__ __align__(16) char regB[17024];     // xt(15872 B) + union{part(512 B)|ttT(1152 B)}
  __shared__ float red_s[16][2];                 // 128 B  -> total 31616 B

  const int tid = threadIdx.x;
  const int lane = tid & 63;
  const int w = tid >> 6;       // 0..3
  const int b = blockIdx.x;
  const int g = lane >> 4;
  const int n = lane & 15;

  _Float16* xt   = (_Float16*)regB;              // 496 rows x 16 halfs = 15872 B (swizzled)
  float*    part = (float*)(regB + 15872);       // [16][4][2] = 512 B, live P3->P4
  _Float16* ttT  = (_Float16*)(regB + 15872);    // [16][36] = 1152 B, live P7->P8
  float*    y0   = (float*)regB;                 // [8][452] = 14464 B, live pre-encoder

  // ---- stage h0, ChComb 1x1 conv + LN + GELU -> h_s ----
  const float* h0 = (const float*)(a.rec + (size_t)b * 14400);
  for (int idx = tid; idx < 3600; idx += 256) {
    int c = idx / 450;
    y0[c * 452 + (idx - c * 450)] = h0[idx];
  }
  __syncthreads();

#pragma unroll 1
  for (int rr = 0; rr < 4; rr++) {
    const int o = w * 4 + rr;
    float wv[8];
#pragma unroll
    for (int c = 0; c < 8; c++) wv[c] = a.ccw[o * 8 + c];
    const float cb0 = a.ccb[o];
    float vals[8];
    float sum = 0.f, sum2 = 0.f;
#pragma unroll
    for (int j = 0; j < 8; j++) {
      int s = lane + 64 * j;
      float v = 0.f;
      if (s < 450) {
        v = cb0;
#pragma unroll
        for (int c = 0; c < 8; c++) v = fmaf(y0[c * 452 + s], wv[c], v);
        sum += v; sum2 = fmaf(v, v, sum2);
      }
      vals[j] = v;
    }
    sum = wred64(sum); sum2 = wred64(sum2);
    float m = sum * (1.f / 450.f);
    float rs = rsqrtf(sum2 * (1.f / 450.f) - m * m + EPS_);
#pragma unroll
    for (int j = 0; j < 8; j++) {
      int s = lane + 64 * j;
      if (s < 450)
        h_s[o][s] = (_Float16)gelu_f((vals[j] - m) * rs * a.cclnw[s] + a.cclnb[s]);
    }
  }
  __syncthreads();

#pragma unroll 1
  for (int e = 0; e < 2; e++) {
    const float* l1w = a.l1w[e]; const float* l1b = a.l1b[e];
    const float* l2w = a.l2w[e]; const float* l2b = a.l2b[e];
    const float* l3w = a.l3w[e]; const float* l3b = a.l3b[e];
    const float* cbp = a.cb[e];
    const float* pb  = a.pb[e];
    const _Float16* wfe  = a.wf  + (size_t)e * 8192;   // 8192 halfs = 16384 B per encoder
    const _Float16* pwfe = a.pwf + (size_t)e * 14848;

    // ---- P1: Xt zero pads + LN1 stats ----
    for (int idx = tid; idx < 368; idx += 256) {
      int rr2 = idx >> 3;
      int rp = (rr2 < 15) ? rr2 : (450 + rr2);
      half2_t z; z[0] = (_Float16)0.f; z[1] = (_Float16)0.f;
      *(half2_t*)(xt + rp * 16 + (idx & 7) * 2) = z;
    }
#pragma unroll 1
    for (int rr = 0; rr < 4; rr++) {
      const int i = w * 4 + rr;
      float sum = 0.f, sum2 = 0.f;
#pragma unroll
      for (int j = 0; j < 8; j++) {
        int s = lane + 64 * j;
        if (s < 450) { float v = (float)h_s[i][s]; sum += v; sum2 = fmaf(v, v, sum2); }
      }
      sum = wred64(sum); sum2 = wred64(sum2);
      float m = sum * (1.f / 450.f);
      float rs = rsqrtf(sum2 * (1.f / 450.f) - m * m + EPS_);
      if (lane == 0) { red_s[i][0] = m; red_s[i][1] = rs; }
    }
    __syncthreads();

    // ---- P2: LN1 apply -> Xt (fp16, transposed, swizzled) ----
    for (int idx = tid; idx < 3600; idx += 256) {
      int s = idx >> 3, ip = idx & 7, i0 = ip * 2;
      float wv = l1w[s], bv = l1b[s];
      float x0 = ((float)h_s[i0][s]     - red_s[i0][0])     * red_s[i0][1]     * wv + bv;
      float x1 = ((float)h_s[i0 + 1][s] - red_s[i0 + 1][0]) * red_s[i0 + 1][1] * wv + bv;
      int rp = s + 15;
      int hh = (ip >> 2) ^ ((rp >> 2) & 1);
      half2_t pk; pk[0] = (_Float16)x0; pk[1] = (_Float16)x1;
      *(half2_t*)(xt + rp * 16 + hh * 8 + (i0 & 7)) = pk;
    }
    __syncthreads();

    // ---- P3: conv via MFMA 16x16x32 f16 (8 tiles/wave); A-frags direct from global ----
    const int hh0 = g & 1;
    const int dt = g >> 1;
    f32x4_t acc[8];
#pragma unroll 1
    for (int pp = 0; pp < 4; pp++) {
      f32x4_t aA = {0.f, 0.f, 0.f, 0.f};
      f32x4_t aB = {0.f, 0.f, 0.f, 0.f};
      int tA = w + 4 * (2 * pp);     if (tA > 28) tA = 28;
      int tB = w + 4 * (2 * pp + 1); if (tB > 28) tB = 28;
      int rbA = tA * 16 + n + dt;
      int rbB = tB * 16 + n + dt;
#pragma unroll
      for (int t = 0; t < 16; t++) {
        half8_t af = *(const half8_t*)(wfe + ((t << 6) + lane) * 8);
        int rA = rbA + 2 * t;
        int rB = rbB + 2 * t;
        half8_t bA = *(const half8_t*)(xt + rA * 16 + ((hh0 ^ ((rA >> 2) & 1)) << 3));
        half8_t bB = *(const half8_t*)(xt + rB * 16 + ((hh0 ^ ((rB >> 2) & 1)) << 3));
        aA = __builtin_amdgcn_mfma_f32_16x16x32_f16(af, bA, aA, 0, 0, 0);
        aB = __builtin_amdgcn_mfma_f32_16x16x32_f16(af, bB, aB, 0, 0, 0);
      }
      acc[2 * pp] = aA; acc[2 * pp + 1] = aB;
    }

    // raw partial sums (cb folded in at P4); part does not alias xt -> no extra barrier
    float s1[4] = {0.f, 0.f, 0.f, 0.f}, s2[4] = {0.f, 0.f, 0.f, 0.f};
#pragma unroll
    for (int tt = 0; tt < 8; tt++) {
      int t0 = w + 4 * tt;
      if (t0 < 29) {
        int s = t0 * 16 + n;
        if (s < 450) {
#pragma unroll
          for (int q = 0; q < 4; q++) {
            float v = acc[tt][q];
            s1[q] += v; s2[q] = fmaf(v, v, s2[q]);
          }
        }
      }
    }
#pragma unroll
    for (int m = 1; m < 16; m <<= 1) {
#pragma unroll
      for (int q = 0; q < 4; q++) {
        s1[q] += __shfl_xor(s1[q], m, 64);
        s2[q] += __shfl_xor(s2[q], m, 64);
      }
    }
    if (n == 0) {
#pragma unroll
      for (int q = 0; q < 4; q++) {
        part[((4 * g + q) * 4 + w) * 2 + 0] = s1[q];
        part[((4 * g + q) * 4 + w) * 2 + 1] = s2[q];
      }
    }
    __syncthreads();

    // ---- P4: finalize LN2 stats (fold conv bias here) ----
    if (tid < 16) {
      float u1 = 0.f, u2 = 0.f;
#pragma unroll
      for (int ww = 0; ww < 4; ww++) {
        u1 += part[(tid * 4 + ww) * 2 + 0];
        u2 += part[(tid * 4 + ww) * 2 + 1];
      }
      float cb0 = cbp[tid];
      float u2p = u2 + 2.f * cb0 * u1 + 450.f * cb0 * cb0;
      float u1p = u1 + 450.f * cb0;
      float m = u1p * (1.f / 450.f);
      float rs = rsqrtf(u2p * (1.f / 450.f) - m * m + EPS_);
      red_s[tid][0] = m; red_s[tid][1] = rs;
    }
    __syncthreads();

    // ---- P5: LN2 + GELU + residual -> h_s (fp16 accumulate) ----
    {
      float mq[4], rq[4], cbq[4];
#pragma unroll
      for (int q = 0; q < 4; q++) {
        mq[q] = red_s[4 * g + q][0]; rq[q] = red_s[4 * g + q][1];
        cbq[q] = cbp[4 * g + q];
      }
#pragma unroll
      for (int tt = 0; tt < 8; tt++) {
        int t0 = w + 4 * tt;
        if (t0 < 29) {
          int s = t0 * 16 + n;
          if (s < 450) {
            float wv = l2w[s], bv = l2b[s];
#pragma unroll
            for (int q = 0; q < 4; q++) {
              int o = 4 * g + q;
              float v = acc[tt][q] + cbq[q];
              h_s[o][s] = (_Float16)((float)h_s[o][s] +
                                     gelu_f((v - mq[q]) * rq[q] * wv + bv));
            }
          }
        }
      }
    }
    __syncthreads();

    // ---- P6: LN3 stats ----
#pragma unroll 1
    for (int rr = 0; rr < 4; rr++) {
      const int c = w * 4 + rr;
      float sum = 0.f, sum2 = 0.f;
#pragma unroll
      for (int j = 0; j < 8; j++) {
        int s = lane + 64 * j;
        if (s < 450) { float v = (float)h_s[c][s]; sum += v; sum2 = fmaf(v, v, sum2); }
      }
      sum = wred64(sum); sum2 = wred64(sum2);
      float m = sum * (1.f / 450.f);
      float rs = rsqrtf(sum2 * (1.f / 450.f) - m * m + EPS_);
      if (lane == 0) { red_s[c][0] = m; red_s[c][1] = rs; }
    }
    __syncthreads();

    // ---- P7: ttT[i][c] = fp16 LN3(h)[c][i], zero pad c in [16,32) ----
    {
      int c = tid >> 4, i = tid & 15;
      float v = ((float)h_s[c][i] - red_s[c][0]) * red_s[c][1] * l3w[i] + l3b[i];
      ttT[i * 36 + c] = (_Float16)v;
      ttT[i * 36 + 16 + c] = (_Float16)0.f;
    }
    __syncthreads();

    // ---- P8: proj via MFMA: h[i][s] += sum_c t2[c][i]*pw[s][c] + pb[s] ----
#pragma unroll
    for (int p = 0; p < 8; p++) {
      int T = w + 4 * p;
      if (T < 29) {
        half8_t afr = *(const half8_t*)(ttT + n * 36 + 8 * g);
        half8_t bfr = *(const half8_t*)(pwfe + (size_t)T * 512 + lane * 8);
        f32x4_t d = {0.f, 0.f, 0.f, 0.f};
        d = __builtin_amdgcn_mfma_f32_16x16x32_f16(afr, bfr, d, 0, 0, 0);
        int s = 16 * T + n;
        if (s < 450) {
          float pbv = pb[s];
#pragma unroll
          for (int q = 0; q < 4; q++) {
            int o = 4 * g + q;
            h_s[o][s] = (_Float16)((float)h_s[o][s] + d[q] + pbv);
          }
        }
      }
    }
    __syncthreads();
  }

  // ---- write hfinal as bf16 over own record ----
  __hip_bfloat16* hf = (__hip_bfloat16*)(a.rec + (size_t)b * 14400);
  for (int idx = tid; idx < 7200; idx += 256) {
    int c = idx / 450;
    hf[idx] = __float2bfloat16((float)h_s[c][idx - c * 450]);
  }
}

// ---------------- K3: MLP head via bf16 MFMA, 4-way K-split, 256 thr ----------------
struct MlpArgs {
  const char* rec;
  const __hip_bfloat16* w1b;
  const float *b1, *lnw, *lnb, *w2, *b2;
  float* out;
};

__global__ __launch_bounds__(256) void k_mlp(MlpArgs a) {
  __shared__ float w2s[12][76];
  __shared__ float b1s[72], lnws[72], lnbs[72];
  __shared__ float accs[4][64][20];   // per-wave K-partials, 20480 B

  const int tid = threadIdx.x;
  const int wv = tid >> 6;
  const int l = tid & 63;
  const int g = l >> 4, n16 = l & 15;
  const int m0 = blockIdx.x * 16;

  for (int i = tid; i < 864; i += 256) { int c = i / 72, j = i - c * 72; w2s[c][j] = a.w2[i]; }
  for (int i = tid; i < 72; i += 256) { b1s[i] = a.b1[i]; lnws[i] = a.lnw[i]; lnbs[i] = a.lnb[i]; }

  const unsigned short* arow =
      (const unsigned short*)(a.rec + (size_t)(m0 + n16) * 14400) + 8 * g;
  const unsigned short* bp[5];
#pragma unroll
  for (int nt = 0; nt < 5; nt++) {
    int r = 16 * nt + n16; if (r > 71) r = 71;
    bp[nt] = (const unsigned short*)a.w1b + (size_t)r * 7200 + 8 * g;
  }

  f32x4_t acc[5];
#pragma unroll
  for (int nt = 0; nt < 5; nt++) acc[nt] = (f32x4_t){0.f, 0.f, 0.f, 0.f};

  const int kt0 = wv * 57;
  const int kt1 = (kt0 + 57 < 225) ? (kt0 + 57) : 225;
#pragma unroll 3
  for (int kt = kt0; kt < kt1; ++kt) {
    bf16x8_t af = *(const bf16x8_t*)(arow + 32 * kt);
#pragma unroll
    for (int nt = 0; nt < 5; nt++) {
      bf16x8_t bf = *(const bf16x8_t*)(bp[nt] + 32 * kt);
      acc[nt] = __builtin_amdgcn_mfma_f32_16x16x32_bf16(af, bf, acc[nt], 0, 0, 0);
    }
  }

#pragma unroll
  for (int nt = 0; nt < 5; nt++)
#pragma unroll
    for (int q = 0; q < 4; q++) accs[wv][l][nt * 4 + q] = acc[nt][q];
  __syncthreads();

  if (wv == 0) {
    // sum K-partials
#pragma unroll
    for (int nt = 0; nt < 5; nt++)
#pragma unroll
      for (int q = 0; q < 4; q++)
        acc[nt][q] = accs[0][l][nt * 4 + q] + accs[1][l][nt * 4 + q] +
                     accs[2][l][nt * 4 + q] + accs[3][l][nt * 4 + q];

    // epilogue: +b1, LN(72), GELU, @w2.T + b2
    float yv[5][4];
    float sum[4] = {0.f, 0.f, 0.f, 0.f}, sum2[4] = {0.f, 0.f, 0.f, 0.f};
#pragma unroll
    for (int nt = 0; nt < 5; nt++) {
      int j = 16 * nt + n16;
      bool val = (j < 72);
#pragma unroll
      for (int q = 0; q < 4; q++) {
        float v = val ? (acc[nt][q] + b1s[j]) : 0.f;
        yv[nt][q] = v;
        sum[q] += v; sum2[q] = fmaf(v, v, sum2[q]);
      }
    }
#pragma unroll
    for (int m = 1; m < 16; m <<= 1) {
#pragma unroll
      for (int q = 0; q < 4; q++) {
        sum[q] += __shfl_xor(sum[q], m, 64);
        sum2[q] += __shfl_xor(sum2[q], m, 64);
      }
    }
    float mm[4], rs[4];
#pragma unroll
    for (int q = 0; q < 4; q++) {
      mm[q] = sum[q] * (1.f / 72.f);
      rs[q] = rsqrtf(sum2[q] * (1.f / 72.f) - mm[q] * mm[q] + EPS_);
    }

    float p[4][12];
#pragma unroll
    for (int q = 0; q < 4; q++)
#pragma unroll
      for (int c = 0; c < 12; c++) p[q][c] = 0.f;

#pragma unroll
    for (int nt = 0; nt < 5; nt++) {
      int j = 16 * nt + n16;
      if (j < 72) {
        float lw = lnws[j], lb = lnbs[j];
#pragma unroll
        for (int q = 0; q < 4; q++) {
          float y2 = gelu_f((yv[nt][q] - mm[q]) * rs[q] * lw + lb);
#pragma unroll
          for (int c = 0; c < 12; c++) p[q][c] = fmaf(y2, w2s[c][j], p[q][c]);
        }
      }
    }
#pragma unroll
    for (int m = 1; m < 16; m <<= 1) {
#pragma unroll
      for (int q = 0; q < 4; q++)
#pragma unroll
        for (int c = 0; c < 12; c++) p[q][c] += __shfl_xor(p[q][c], m, 64);
    }

    if (n16 == 0) {
#pragma unroll
      for (int q = 0; q < 4; q++) {
        int m = m0 + 4 * g + q;
        float4 o0 = make_float4(p[q][0] + a.b2[0], p[q][1] + a.b2[1], p[q][2] + a.b2[2], p[q][3] + a.b2[3]);
        float4 o1 = make_float4(p[q][4] + a.b2[4], p[q][5] + a.b2[5], p[q][6] + a.b2[6], p[q][7] + a.b2[7]);
        float4 o2 = make_float4(p[q][8] + a.b2[8], p[q][9] + a.b2[9], p[q][10] + a.b2[10], p[q][11] + a.b2[11]);
        *(float4*)&a.out[(size_t)m * 12]     = o0;
        *(float4*)&a.out[(size_t)m * 12 + 4] = o1;
        *(float4*)&a.out[(size_t)m * 12 + 8] = o2;
      }
    }
  }
}

// ---------------- launch ----------------
extern "C" void kernel_launch(void* const* d_in, const int* in_sizes, int n_in,
                              void* d_out, int out_size, void* d_ws, size_t ws_size,
                              hipStream_t stream) {
  const float* x = (const float*)d_in[0];

  _Float16* tabT = (_Float16*)d_ws;                              // 450*1024*2 = 921600 B
  _Float16* wf  = (_Float16*)((char*)d_ws + 921600);             // 65536 B
  _Float16* pwf = (_Float16*)((char*)d_ws + 987136);             // 59392 B
  __hip_bfloat16* w1b = (__hip_bfloat16*)((char*)d_ws + 1046528); // 1036800 B -> ends 2083328
  char* rec = (char*)d_ws + (size_t)(2 * 1024 * 1024);           // 8192 * 14400 B

  k_table<<<1800, 256, 0, stream>>>(tabT);
  k_prep<<<2269, 256, 0, stream>>>((const float*)d_in[11], (const float*)d_in[21],
                                   (const float*)d_in[13], (const float*)d_in[23],
                                   (const float*)d_in[25], wf, pwf, w1b);
  k_dft<<<2048, 256, 0, stream>>>(x, tabT, (float*)rec);

  NetArgs na;
  na.ccw = (const float*)d_in[1];
  na.ccb = (const float*)d_in[2];
  na.cclnw = (const float*)d_in[3];
  na.cclnb = (const float*)d_in[4];
  for (int e = 0; e < 2; e++) {
    int o = 5 + e * 10;
    na.l1w[e] = (const float*)d_in[o + 0];
    na.l1b[e] = (const float*)d_in[o + 1];
    na.l2w[e] = (const float*)d_in[o + 2];
    na.l2b[e] = (const float*)d_in[o + 3];
    na.l3w[e] = (const float*)d_in[o + 4];
    na.l3b[e] = (const float*)d_in[o + 5];
    na.cb[e]  = (const float*)d_in[o + 7];
    na.pb[e]  = (const float*)d_in[o + 9];
  }
  na.wf = wf;
  na.pwf = pwf;
  na.rec = rec;
  k_net<<<8192, 256, 0, stream>>>(na);

  MlpArgs ma;
  ma.rec = rec;
  ma.w1b = w1b;
  ma.b1 = (const float*)d_in[26];
  ma.lnw = (const float*)d_in[27];
  ma.lnb = (const float*)d_in[28];
  ma.w2 = (const float*)d_in[29];
  ma.b2 = (const float*)d_in[30];
  ma.out = (float*)d_out;
  k_mlp<<<512, 256, 0, stream>>>(ma);
}

// Round 15
// 1059.213 us; speedup vs baseline: 1.1298x; 1.1298x over previous
//
#include <hip/hip_runtime.h>
#include <hip/hip_bf16.h>
#include <math.h>

#define EPS_ 1e-5f

typedef _Float16 half8_t __attribute__((ext_vector_type(8)));
typedef _Float16 half2_t __attribute__((ext_vector_type(2)));
typedef float f32x4_t __attribute__((ext_vector_type(4)));
typedef short bf16x8_t __attribute__((ext_vector_type(8)));

// fast GELU (tanh form), |err| vs exact erf-GELU <~4e-4; clamped for inf-safety
__device__ __forceinline__ float gelu_f(float x) {
  float u2 = x * fmaf(0.0713548162f, x * x, 1.5957691216f);
  u2 = fminf(u2, 80.f);
  float e = __expf(u2);
  return x - x / (1.f + e);
}

__device__ __forceinline__ float wred64(float v) {
#pragma unroll
  for (int m = 32; m > 0; m >>= 1) v += __shfl_xor(v, m, 64);
  return v;
}

// ---------------- K0: fp16 transposed DFT table tabT[s][t], s in [0,450) ----------------
__global__ void k_table(_Float16* __restrict__ tabT) {
  int idx = blockIdx.x * 256 + threadIdx.x;
  if (idx >= 450 * 1024) return;
  int s = idx >> 10;
  int t = idx & 1023;
  int f = (s < 225) ? (32 + s) : (s - 225 + 32);
  int ph = (f * t) & 1023;
  float ang = (float)ph * (6.2831853071795864769e0f / 1024.0f);
  float v = ((s < 225) ? cosf(ang) : -sinf(ang)) * (1.0f / 1024.0f);
  tabT[idx] = (_Float16)v;
}

// ---------------- K0b: pack conv + proj weights (fp16 fragments) + w1 bf16 copy ----------------
__global__ void k_prep(const float* __restrict__ cw0, const float* __restrict__ cw1,
                       const float* __restrict__ pw0, const float* __restrict__ pw1,
                       const float* __restrict__ w1,
                       _Float16* __restrict__ wf, _Float16* __restrict__ pwf,
                       __hip_bfloat16* __restrict__ w1b) {
  int idx = blockIdx.x * 256 + threadIdx.x;
  if (idx < 32768) {
    int j = idx & 7;
    int l = (idx >> 3) & 63;
    int t = (idx >> 9) & 15;
    int e = idx >> 13;
    int g = l >> 4, o = l & 15;
    int i = 8 * (g & 1) + j;
    int k = 2 * t + (g >> 1);
    const float* cw = e ? cw1 : cw0;
    float v = (k < 31) ? cw[(o * 16 + i) * 31 + k] : 0.f;
    wf[idx] = (_Float16)v;
  } else if (idx < 62464) {
    int idx2 = idx - 32768;
    int e = idx2 / 14848;
    int r = idx2 - e * 14848;
    int T = r >> 9;
    int l = (r >> 3) & 63;
    int j = r & 7;
    int g = l >> 4;
    int c = 8 * g + j;
    int s = 16 * T + (l & 15);
    const float* pws = e ? pw1 : pw0;
    float v = (c < 16 && s < 450) ? pws[s * 16 + c] : 0.f;
    pwf[idx2] = (_Float16)v;
  } else if (idx < 62464 + 518400) {
    int idx2 = idx - 62464;
    w1b[idx2] = __float2bfloat16(w1[idx2]);
  }
}

// ---------------- K1: DFT GEMM via fp16 MFMA, split x = hi + lo ----------------
__global__ __launch_bounds__(256) void k_dft(const float* __restrict__ X,
                                             const _Float16* __restrict__ tabT,
                                             float* __restrict__ C) {
  __shared__ _Float16 As[2][32][72];   // [hi/lo][m][k] pitch 72 halfs

  const int tid = threadIdx.x;
  const int l = tid & 63;
  const int w = tid >> 6;        // wave -> n-strip base 128*w
  const int g = l >> 4;
  const int n16 = l & 15;
  const int m0 = blockIdx.x * 32;

  const int sm = tid >> 3;          // staging row 0..31
  const int sk = (tid & 7) * 4;     // staging k 0..28

  f32x4_t acc[2][8];
#pragma unroll
  for (int fi = 0; fi < 2; fi++)
#pragma unroll
    for (int nj = 0; nj < 8; nj++) acc[fi][nj] = (f32x4_t){0.f, 0.f, 0.f, 0.f};

  const float* xrow = X + (size_t)(m0 + sm) * 1024 + sk;

  for (int k0 = 0; k0 < 1024; k0 += 64) {
    float4 xa = *(const float4*)(xrow + k0);
    float4 xb = *(const float4*)(xrow + k0 + 32);
    __syncthreads();
    {
      _Float16 ha[4], la[4], hb[4], lb[4];
      float va[4] = {xa.x, xa.y, xa.z, xa.w};
      float vb[4] = {xb.x, xb.y, xb.z, xb.w};
#pragma unroll
      for (int q = 0; q < 4; q++) {
        ha[q] = (_Float16)va[q];
        la[q] = (_Float16)(va[q] - (float)ha[q]);
        hb[q] = (_Float16)vb[q];
        lb[q] = (_Float16)(vb[q] - (float)hb[q]);
      }
      *(half2_t*)&As[0][sm][sk]      = *(half2_t*)&ha[0];
      *(half2_t*)&As[0][sm][sk + 2]  = *(half2_t*)&ha[2];
      *(half2_t*)&As[1][sm][sk]      = *(half2_t*)&la[0];
      *(half2_t*)&As[1][sm][sk + 2]  = *(half2_t*)&la[2];
      *(half2_t*)&As[0][sm][sk + 32] = *(half2_t*)&hb[0];
      *(half2_t*)&As[0][sm][sk + 34] = *(half2_t*)&hb[2];
      *(half2_t*)&As[1][sm][sk + 32] = *(half2_t*)&lb[0];
      *(half2_t*)&As[1][sm][sk + 34] = *(half2_t*)&lb[2];
    }
    __syncthreads();
#pragma unroll
    for (int ks = 0; ks < 2; ks++) {
      half8_t a_hi[2], a_lo[2];
#pragma unroll
      for (int fi = 0; fi < 2; fi++) {
        a_hi[fi] = *(const half8_t*)&As[0][16 * fi + n16][ks * 32 + 8 * g];
        a_lo[fi] = *(const half8_t*)&As[1][16 * fi + n16][ks * 32 + 8 * g];
      }
#pragma unroll
      for (int nj = 0; nj < 8; nj++) {
        int s = 128 * w + 16 * nj + n16;
        int sc = (s < 450) ? s : 449;
        half8_t bf = *(const half8_t*)(tabT + (size_t)sc * 1024 + k0 + ks * 32 + 8 * g);
#pragma unroll
        for (int fi = 0; fi < 2; fi++) {
          acc[fi][nj] = __builtin_amdgcn_mfma_f32_16x16x32_f16(a_hi[fi], bf, acc[fi][nj], 0, 0, 0);
          acc[fi][nj] = __builtin_amdgcn_mfma_f32_16x16x32_f16(a_lo[fi], bf, acc[fi][nj], 0, 0, 0);
        }
      }
    }
  }

#pragma unroll
  for (int fi = 0; fi < 2; fi++)
#pragma unroll
    for (int nj = 0; nj < 8; nj++) {
      int s = 128 * w + 16 * nj + n16;
      if (s < 450) {
#pragma unroll
        for (int q = 0; q < 4; q++) {
          int m = m0 + 16 * fi + 4 * g + q;
          C[(size_t)m * 450 + s] = acc[fi][nj][q];
        }
      }
    }
}

// ---------------- K2: fused network, 256 thr / 4 waves, fp16 residual in LDS, 4 blk/CU ----------------
struct NetArgs {
  const float *ccw, *ccb, *cclnw, *cclnb;
  const float *l1w[2], *l1b[2], *l2w[2], *l2b[2], *l3w[2], *l3b[2];
  const float *cb[2], *pb[2];
  const _Float16* wf;    // [2][16][64][8] conv A-fragments (global, L1-hot)
  const _Float16* pwf;   // [2][29][64][8] proj B-fragments
  char* rec;
};

__global__ __launch_bounds__(256, 4) void k_net(NetArgs a) {
  __shared__ _Float16 h_s[16][452];              // 14464 B (residual stream, fp16)
  __shared__ __align__(16) char regB[17024];     // xt(15872 B) + union{part(512 B)|ttT(1152 B)}
  __shared__ float red_s[16][2];                 // 128 B  -> total 31616 B

  const int tid = threadIdx.x;
  const int lane = tid & 63;
  const int w = tid >> 6;       // 0..3
  const int b = blockIdx.x;
  const int g = lane >> 4;
  const int n = lane & 15;

  _Float16* xt   = (_Float16*)regB;              // 496 rows x 16 halfs = 15872 B (swizzled)
  float*    part = (float*)(regB + 15872);       // [16][4][2] = 512 B, live P3->P4
  _Float16* ttT  = (_Float16*)(regB + 15872);    // [16][36] = 1152 B, live P7->P8
  float*    y0   = (float*)regB;                 // [8][452] = 14464 B, live pre-encoder

  // ---- stage h0, ChComb 1x1 conv + LN + GELU -> h_s ----
  const float* h0 = (const float*)(a.rec + (size_t)b * 14400);
  for (int idx = tid; idx < 3600; idx += 256) {
    int c = idx / 450;
    y0[c * 452 + (idx - c * 450)] = h0[idx];
  }
  __syncthreads();

#pragma unroll 1
  for (int rr = 0; rr < 4; rr++) {
    const int o = w * 4 + rr;
    float wv[8];
#pragma unroll
    for (int c = 0; c < 8; c++) wv[c] = a.ccw[o * 8 + c];
    const float cb0 = a.ccb[o];
    float vals[8];
    float sum = 0.f, sum2 = 0.f;
#pragma unroll
    for (int j = 0; j < 8; j++) {
      int s = lane + 64 * j;
      float v = 0.f;
      if (s < 450) {
        v = cb0;
#pragma unroll
        for (int c = 0; c < 8; c++) v = fmaf(y0[c * 452 + s], wv[c], v);
        sum += v; sum2 = fmaf(v, v, sum2);
      }
      vals[j] = v;
    }
    sum = wred64(sum); sum2 = wred64(sum2);
    float m = sum * (1.f / 450.f);
    float rs = rsqrtf(sum2 * (1.f / 450.f) - m * m + EPS_);
#pragma unroll
    for (int j = 0; j < 8; j++) {
      int s = lane + 64 * j;
      if (s < 450)
        h_s[o][s] = (_Float16)gelu_f((vals[j] - m) * rs * a.cclnw[s] + a.cclnb[s]);
    }
  }
  __syncthreads();

#pragma unroll 1
  for (int e = 0; e < 2; e++) {
    const float* l1w = a.l1w[e]; const float* l1b = a.l1b[e];
    const float* l2w = a.l2w[e]; const float* l2b = a.l2b[e];
    const float* l3w = a.l3w[e]; const float* l3b = a.l3b[e];
    const float* cbp = a.cb[e];
    const float* pb  = a.pb[e];
    const _Float16* wfe  = a.wf  + (size_t)e * 8192;   // 8192 halfs = 16384 B per encoder
    const _Float16* pwfe = a.pwf + (size_t)e * 14848;

    // ---- P1: Xt zero pads + LN1 stats ----
    for (int idx = tid; idx < 368; idx += 256) {
      int rr2 = idx >> 3;
      int rp = (rr2 < 15) ? rr2 : (450 + rr2);
      half2_t z; z[0] = (_Float16)0.f; z[1] = (_Float16)0.f;
      *(half2_t*)(xt + rp * 16 + (idx & 7) * 2) = z;
    }
#pragma unroll 1
    for (int rr = 0; rr < 4; rr++) {
      const int i = w * 4 + rr;
      float sum = 0.f, sum2 = 0.f;
#pragma unroll
      for (int j = 0; j < 8; j++) {
        int s = lane + 64 * j;
        if (s < 450) { float v = (float)h_s[i][s]; sum += v; sum2 = fmaf(v, v, sum2); }
      }
      sum = wred64(sum); sum2 = wred64(sum2);
      float m = sum * (1.f / 450.f);
      float rs = rsqrtf(sum2 * (1.f / 450.f) - m * m + EPS_);
      if (lane == 0) { red_s[i][0] = m; red_s[i][1] = rs; }
    }
    __syncthreads();

    // ---- P2: LN1 apply -> Xt (fp16, transposed, swizzled) ----
    for (int idx = tid; idx < 3600; idx += 256) {
      int s = idx >> 3, ip = idx & 7, i0 = ip * 2;
      float wv = l1w[s], bv = l1b[s];
      float x0 = ((float)h_s[i0][s]     - red_s[i0][0])     * red_s[i0][1]     * wv + bv;
      float x1 = ((float)h_s[i0 + 1][s] - red_s[i0 + 1][0]) * red_s[i0 + 1][1] * wv + bv;
      int rp = s + 15;
      int hh = (ip >> 2) ^ ((rp >> 2) & 1);
      half2_t pk; pk[0] = (_Float16)x0; pk[1] = (_Float16)x1;
      *(half2_t*)(xt + rp * 16 + hh * 8 + (i0 & 7)) = pk;
    }
    __syncthreads();

    // ---- P3: conv via MFMA 16x16x32 f16 (8 tiles/wave); A-frags direct from global ----
    const int hh0 = g & 1;
    const int dt = g >> 1;
    f32x4_t acc[8];
#pragma unroll 1
    for (int pp = 0; pp < 4; pp++) {
      f32x4_t aA = {0.f, 0.f, 0.f, 0.f};
      f32x4_t aB = {0.f, 0.f, 0.f, 0.f};
      int tA = w + 4 * (2 * pp);     if (tA > 28) tA = 28;
      int tB = w + 4 * (2 * pp + 1); if (tB > 28) tB = 28;
      int rbA = tA * 16 + n + dt;
      int rbB = tB * 16 + n + dt;
#pragma unroll
      for (int t = 0; t < 16; t++) {
        half8_t af = *(const half8_t*)(wfe + ((t << 6) + lane) * 8);
        int rA = rbA + 2 * t;
        int rB = rbB + 2 * t;
        half8_t bA = *(const half8_t*)(xt + rA * 16 + ((hh0 ^ ((rA >> 2) & 1)) << 3));
        half8_t bB = *(const half8_t*)(xt + rB * 16 + ((hh0 ^ ((rB >> 2) & 1)) << 3));
        aA = __builtin_amdgcn_mfma_f32_16x16x32_f16(af, bA, aA, 0, 0, 0);
        aB = __builtin_amdgcn_mfma_f32_16x16x32_f16(af, bB, aB, 0, 0, 0);
      }
      acc[2 * pp] = aA; acc[2 * pp + 1] = aB;
    }

    // raw partial sums (cb folded in at P4); part does not alias xt -> no extra barrier
    float s1[4] = {0.f, 0.f, 0.f, 0.f}, s2[4] = {0.f, 0.f, 0.f, 0.f};
#pragma unroll
    for (int tt = 0; tt < 8; tt++) {
      int t0 = w + 4 * tt;
      if (t0 < 29) {
        int s = t0 * 16 + n;
        if (s < 450) {
#pragma unroll
          for (int q = 0; q < 4; q++) {
            float v = acc[tt][q];
            s1[q] += v; s2[q] = fmaf(v, v, s2[q]);
          }
        }
      }
    }
#pragma unroll
    for (int m = 1; m < 16; m <<= 1) {
#pragma unroll
      for (int q = 0; q < 4; q++) {
        s1[q] += __shfl_xor(s1[q], m, 64);
        s2[q] += __shfl_xor(s2[q], m, 64);
      }
    }
    if (n == 0) {
#pragma unroll
      for (int q = 0; q < 4; q++) {
        part[((4 * g + q) * 4 + w) * 2 + 0] = s1[q];
        part[((4 * g + q) * 4 + w) * 2 + 1] = s2[q];
      }
    }
    __syncthreads();

    // ---- P4: finalize LN2 stats (fold conv bias here) ----
    if (tid < 16) {
      float u1 = 0.f, u2 = 0.f;
#pragma unroll
      for (int ww = 0; ww < 4; ww++) {
        u1 += part[(tid * 4 + ww) * 2 + 0];
        u2 += part[(tid * 4 + ww) * 2 + 1];
      }
      float cb0 = cbp[tid];
      float u2p = u2 + 2.f * cb0 * u1 + 450.f * cb0 * cb0;
      float u1p = u1 + 450.f * cb0;
      float m = u1p * (1.f / 450.f);
      float rs = rsqrtf(u2p * (1.f / 450.f) - m * m + EPS_);
      red_s[tid][0] = m; red_s[tid][1] = rs;
    }
    __syncthreads();

    // ---- P5: LN2 + GELU + residual -> h_s (fp16 accumulate) ----
    {
      float mq[4], rq[4], cbq[4];
#pragma unroll
      for (int q = 0; q < 4; q++) {
        mq[q] = red_s[4 * g + q][0]; rq[q] = red_s[4 * g + q][1];
        cbq[q] = cbp[4 * g + q];
      }
#pragma unroll
      for (int tt = 0; tt < 8; tt++) {
        int t0 = w + 4 * tt;
        if (t0 < 29) {
          int s = t0 * 16 + n;
          if (s < 450) {
            float wv = l2w[s], bv = l2b[s];
#pragma unroll
            for (int q = 0; q < 4; q++) {
              int o = 4 * g + q;
              float v = acc[tt][q] + cbq[q];
              h_s[o][s] = (_Float16)((float)h_s[o][s] +
                                     gelu_f((v - mq[q]) * rq[q] * wv + bv));
            }
          }
        }
      }
    }
    __syncthreads();

    // ---- P6: LN3 stats ----
#pragma unroll 1
    for (int rr = 0; rr < 4; rr++) {
      const int c = w * 4 + rr;
      float sum = 0.f, sum2 = 0.f;
#pragma unroll
      for (int j = 0; j < 8; j++) {
        int s = lane + 64 * j;
        if (s < 450) { float v = (float)h_s[c][s]; sum += v; sum2 = fmaf(v, v, sum2); }
      }
      sum = wred64(sum); sum2 = wred64(sum2);
      float m = sum * (1.f / 450.f);
      float rs = rsqrtf(sum2 * (1.f / 450.f) - m * m + EPS_);
      if (lane == 0) { red_s[c][0] = m; red_s[c][1] = rs; }
    }
    __syncthreads();

    // ---- P7: ttT[i][c] = fp16 LN3(h)[c][i], zero pad c in [16,32) ----
    {
      int c = tid >> 4, i = tid & 15;
      float v = ((float)h_s[c][i] - red_s[c][0]) * red_s[c][1] * l3w[i] + l3b[i];
      ttT[i * 36 + c] = (_Float16)v;
      ttT[i * 36 + 16 + c] = (_Float16)0.f;
    }
    __syncthreads();

    // ---- P8: proj via MFMA: h[i][s] += sum_c t2[c][i]*pw[s][c] + pb[s] ----
#pragma unroll
    for (int p = 0; p < 8; p++) {
      int T = w + 4 * p;
      if (T < 29) {
        half8_t afr = *(const half8_t*)(ttT + n * 36 + 8 * g);
        half8_t bfr = *(const half8_t*)(pwfe + (size_t)T * 512 + lane * 8);
        f32x4_t d = {0.f, 0.f, 0.f, 0.f};
        d = __builtin_amdgcn_mfma_f32_16x16x32_f16(afr, bfr, d, 0, 0, 0);
        int s = 16 * T + n;
        if (s < 450) {
          float pbv = pb[s];
#pragma unroll
          for (int q = 0; q < 4; q++) {
            int o = 4 * g + q;
            h_s[o][s] = (_Float16)((float)h_s[o][s] + d[q] + pbv);
          }
        }
      }
    }
    __syncthreads();
  }

  // ---- write hfinal as bf16 over own record ----
  __hip_bfloat16* hf = (__hip_bfloat16*)(a.rec + (size_t)b * 14400);
  for (int idx = tid; idx < 7200; idx += 256) {
    int c = idx / 450;
    hf[idx] = __float2bfloat16((float)h_s[c][idx - c * 450]);
  }
}

// ---------------- K3: MLP head via bf16 MFMA, 4-way K-split, 256 thr ----------------
struct MlpArgs {
  const char* rec;
  const __hip_bfloat16* w1b;
  const float *b1, *lnw, *lnb, *w2, *b2;
  float* out;
};

__global__ __launch_bounds__(256) void k_mlp(MlpArgs a) {
  __shared__ float w2s[12][76];
  __shared__ float b1s[72], lnws[72], lnbs[72];
  __shared__ float accs[4][64][20];   // per-wave K-partials, 20480 B

  const int tid = threadIdx.x;
  const int wv = tid >> 6;
  const int l = tid & 63;
  const int g = l >> 4, n16 = l & 15;
  const int m0 = blockIdx.x * 16;

  for (int i = tid; i < 864; i += 256) { int c = i / 72, j = i - c * 72; w2s[c][j] = a.w2[i]; }
  for (int i = tid; i < 72; i += 256) { b1s[i] = a.b1[i]; lnws[i] = a.lnw[i]; lnbs[i] = a.lnb[i]; }

  const unsigned short* arow =
      (const unsigned short*)(a.rec + (size_t)(m0 + n16) * 14400) + 8 * g;
  const unsigned short* bp[5];
#pragma unroll
  for (int nt = 0; nt < 5; nt++) {
    int r = 16 * nt + n16; if (r > 71) r = 71;
    bp[nt] = (const unsigned short*)a.w1b + (size_t)r * 7200 + 8 * g;
  }

  f32x4_t acc[5];
#pragma unroll
  for (int nt = 0; nt < 5; nt++) acc[nt] = (f32x4_t){0.f, 0.f, 0.f, 0.f};

  const int kt0 = wv * 57;
  const int kt1 = (kt0 + 57 < 225) ? (kt0 + 57) : 225;
#pragma unroll 3
  for (int kt = kt0; kt < kt1; ++kt) {
    bf16x8_t af = *(const bf16x8_t*)(arow + 32 * kt);
#pragma unroll
    for (int nt = 0; nt < 5; nt++) {
      bf16x8_t bf = *(const bf16x8_t*)(bp[nt] + 32 * kt);
      acc[nt] = __builtin_amdgcn_mfma_f32_16x16x32_bf16(af, bf, acc[nt], 0, 0, 0);
    }
  }

#pragma unroll
  for (int nt = 0; nt < 5; nt++)
#pragma unroll
    for (int q = 0; q < 4; q++) accs[wv][l][nt * 4 + q] = acc[nt][q];
  __syncthreads();

  if (wv == 0) {
    // sum K-partials
#pragma unroll
    for (int nt = 0; nt < 5; nt++)
#pragma unroll
      for (int q = 0; q < 4; q++)
        acc[nt][q] = accs[0][l][nt * 4 + q] + accs[1][l][nt * 4 + q] +
                     accs[2][l][nt * 4 + q] + accs[3][l][nt * 4 + q];

    // epilogue: +b1, LN(72), GELU, @w2.T + b2
    float yv[5][4];
    float sum[4] = {0.f, 0.f, 0.f, 0.f}, sum2[4] = {0.f, 0.f, 0.f, 0.f};
#pragma unroll
    for (int nt = 0; nt < 5; nt++) {
      int j = 16 * nt + n16;
      bool val = (j < 72);
#pragma unroll
      for (int q = 0; q < 4; q++) {
        float v = val ? (acc[nt][q] + b1s[j]) : 0.f;
        yv[nt][q] = v;
        sum[q] += v; sum2[q] = fmaf(v, v, sum2[q]);
      }
    }
#pragma unroll
    for (int m = 1; m < 16; m <<= 1) {
#pragma unroll
      for (int q = 0; q < 4; q++) {
        sum[q] += __shfl_xor(sum[q], m, 64);
        sum2[q] += __shfl_xor(sum2[q], m, 64);
      }
    }
    float mm[4], rs[4];
#pragma unroll
    for (int q = 0; q < 4; q++) {
      mm[q] = sum[q] * (1.f / 72.f);
      rs[q] = rsqrtf(sum2[q] * (1.f / 72.f) - mm[q] * mm[q] + EPS_);
    }

    float p[4][12];
#pragma unroll
    for (int q = 0; q < 4; q++)
#pragma unroll
      for (int c = 0; c < 12; c++) p[q][c] = 0.f;

#pragma unroll
    for (int nt = 0; nt < 5; nt++) {
      int j = 16 * nt + n16;
      if (j < 72) {
        float lw = lnws[j], lb = lnbs[j];
#pragma unroll
        for (int q = 0; q < 4; q++) {
          float y2 = gelu_f((yv[nt][q] - mm[q]) * rs[q] * lw + lb);
#pragma unroll
          for (int c = 0; c < 12; c++) p[q][c] = fmaf(y2, w2s[c][j], p[q][c]);
        }
      }
    }
#pragma unroll
    for (int m = 1; m < 16; m <<= 1) {
#pragma unroll
      for (int q = 0; q < 4; q++)
#pragma unroll
        for (int c = 0; c < 12; c++) p[q][c] += __shfl_xor(p[q][c], m, 64);
    }

    if (n16 == 0) {
#pragma unroll
      for (int q = 0; q < 4; q++) {
        int m = m0 + 4 * g + q;
        float4 o0 = make_float4(p[q][0] + a.b2[0], p[q][1] + a.b2[1], p[q][2] + a.b2[2], p[q][3] + a.b2[3]);
        float4 o1 = make_float4(p[q][4] + a.b2[4], p[q][5] + a.b2[5], p[q][6] + a.b2[6], p[q][7] + a.b2[7]);
        float4 o2 = make_float4(p[q][8] + a.b2[8], p[q][9] + a.b2[9], p[q][10] + a.b2[10], p[q][11] + a.b2[11]);
        *(float4*)&a.out[(size_t)m * 12]     = o0;
        *(float4*)&a.out[(size_t)m * 12 + 4] = o1;
        *(float4*)&a.out[(size_t)m * 12 + 8] = o2;
      }
    }
  }
}

// ---------------- launch ----------------
extern "C" void kernel_launch(void* const* d_in, const int* in_sizes, int n_in,
                              void* d_out, int out_size, void* d_ws, size_t ws_size,
                              hipStream_t stream) {
  const float* x = (const float*)d_in[0];

  _Float16* tabT = (_Float16*)d_ws;                              // 450*1024*2 = 921600 B
  _Float16* wf  = (_Float16*)((char*)d_ws + 921600);             // 65536 B
  _Float16* pwf = (_Float16*)((char*)d_ws + 987136);             // 59392 B
  __hip_bfloat16* w1b = (__hip_bfloat16*)((char*)d_ws + 1046528); // 1036800 B -> ends 2083328
  char* rec = (char*)d_ws + (size_t)(2 * 1024 * 1024);           // 8192 * 14400 B

  k_table<<<1800, 256, 0, stream>>>(tabT);
  k_prep<<<2269, 256, 0, stream>>>((const float*)d_in[11], (const float*)d_in[21],
                                   (const float*)d_in[13], (const float*)d_in[23],
                                   (const float*)d_in[25], wf, pwf, w1b);
  k_dft<<<2048, 256, 0, stream>>>(x, tabT, (float*)rec);

  NetArgs na;
  na.ccw = (const float*)d_in[1];
  na.ccb = (const float*)d_in[2];
  na.cclnw = (const float*)d_in[3];
  na.cclnb = (const float*)d_in[4];
  for (int e = 0; e < 2; e++) {
    int o = 5 + e * 10;
    na.l1w[e] = (const float*)d_in[o + 0];
    na.l1b[e] = (const float*)d_in[o + 1];
    na.l2w[e] = (const float*)d_in[o + 2];
    na.l2b[e] = (const float*)d_in[o + 3];
    na.l3w[e] = (const float*)d_in[o + 4];
    na.l3b[e] = (const float*)d_in[o + 5];
    na.cb[e]  = (const float*)d_in[o + 7];
    na.pb[e]  = (const float*)d_in[o + 9];
  }
  na.wf = wf;
  na.pwf = pwf;
  na.rec = rec;
  k_net<<<8192, 256, 0, stream>>>(na);

  MlpArgs ma;
  ma.rec = rec;
  ma.w1b = w1b;
  ma.b1 = (const float*)d_in[26];
  ma.lnw = (const float*)d_in[27];
  ma.lnb = (const float*)d_in[28];
  ma.w2 = (const float*)d_in[29];
  ma.b2 = (const float*)d_in[30];
  ma.out = (float*)d_out;
  k_mlp<<<512, 256, 0, stream>>>(ma);
}

// Round 16
// 984.065 us; speedup vs baseline: 1.2160x; 1.0764x over previous
//
#include <hip/hip_runtime.h>
#include <hip/hip_bf16.h>
#include <math.h>

#define EPS_ 1e-5f

typedef _Float16 half8_t __attribute__((ext_vector_type(8)));
typedef _Float16 half2_t __attribute__((ext_vector_type(2)));
typedef float f32x4_t __attribute__((ext_vector_type(4)));
typedef short bf16x8_t __attribute__((ext_vector_type(8)));

// fast GELU (tanh form), |err| vs exact erf-GELU <~4e-4; clamped for inf-safety
__device__ __forceinline__ float gelu_f(float x) {
  float u2 = x * fmaf(0.0713548162f, x * x, 1.5957691216f);
  u2 = fminf(u2, 80.f);
  float e = __expf(u2);
  return x - x / (1.f + e);
}

__device__ __forceinline__ float wred64(float v) {
#pragma unroll
  for (int m = 32; m > 0; m >>= 1) v += __shfl_xor(v, m, 64);
  return v;
}

// ---------------- K0: fp16 transposed DFT table tabT[s][t], s in [0,450) ----------------
__global__ void k_table(_Float16* __restrict__ tabT) {
  int idx = blockIdx.x * 256 + threadIdx.x;
  if (idx >= 450 * 1024) return;
  int s = idx >> 10;
  int t = idx & 1023;
  int f = (s < 225) ? (32 + s) : (s - 225 + 32);
  int ph = (f * t) & 1023;
  float ang = (float)ph * (6.2831853071795864769e0f / 1024.0f);
  float v = ((s < 225) ? cosf(ang) : -sinf(ang)) * (1.0f / 1024.0f);
  tabT[idx] = (_Float16)v;
}

// ---------------- K0b: pack conv + proj weights (fp16 fragments) + w1 bf16 copy ----------------
__global__ void k_prep(const float* __restrict__ cw0, const float* __restrict__ cw1,
                       const float* __restrict__ pw0, const float* __restrict__ pw1,
                       const float* __restrict__ w1,
                       _Float16* __restrict__ wf, _Float16* __restrict__ pwf,
                       __hip_bfloat16* __restrict__ w1b) {
  int idx = blockIdx.x * 256 + threadIdx.x;
  if (idx < 32768) {
    int j = idx & 7;
    int l = (idx >> 3) & 63;
    int t = (idx >> 9) & 15;
    int e = idx >> 13;
    int g = l >> 4, o = l & 15;
    int i = 8 * (g & 1) + j;
    int k = 2 * t + (g >> 1);
    const float* cw = e ? cw1 : cw0;
    float v = (k < 31) ? cw[(o * 16 + i) * 31 + k] : 0.f;
    wf[idx] = (_Float16)v;
  } else if (idx < 62464) {
    int idx2 = idx - 32768;
    int e = idx2 / 14848;
    int r = idx2 - e * 14848;
    int T = r >> 9;
    int l = (r >> 3) & 63;
    int j = r & 7;
    int g = l >> 4;
    int c = 8 * g + j;
    int s = 16 * T + (l & 15);
    const float* pws = e ? pw1 : pw0;
    float v = (c < 16 && s < 450) ? pws[s * 16 + c] : 0.f;
    pwf[idx2] = (_Float16)v;
  } else if (idx < 62464 + 518400) {
    int idx2 = idx - 62464;
    w1b[idx2] = __float2bfloat16(w1[idx2]);
  }
}

// ---------------- K1: DFT GEMM via fp16 MFMA, split x = hi + lo ----------------
__global__ __launch_bounds__(256) void k_dft(const float* __restrict__ X,
                                             const _Float16* __restrict__ tabT,
                                             float* __restrict__ C) {
  __shared__ _Float16 As[2][32][72];   // [hi/lo][m][k] pitch 72 halfs

  const int tid = threadIdx.x;
  const int l = tid & 63;
  const int w = tid >> 6;        // wave -> n-strip base 128*w
  const int g = l >> 4;
  const int n16 = l & 15;
  const int m0 = blockIdx.x * 32;

  const int sm = tid >> 3;          // staging row 0..31
  const int sk = (tid & 7) * 4;     // staging k 0..28

  f32x4_t acc[2][8];
#pragma unroll
  for (int fi = 0; fi < 2; fi++)
#pragma unroll
    for (int nj = 0; nj < 8; nj++) acc[fi][nj] = (f32x4_t){0.f, 0.f, 0.f, 0.f};

  const float* xrow = X + (size_t)(m0 + sm) * 1024 + sk;

  for (int k0 = 0; k0 < 1024; k0 += 64) {
    float4 xa = *(const float4*)(xrow + k0);
    float4 xb = *(const float4*)(xrow + k0 + 32);
    __syncthreads();
    {
      _Float16 ha[4], la[4], hb[4], lb[4];
      float va[4] = {xa.x, xa.y, xa.z, xa.w};
      float vb[4] = {xb.x, xb.y, xb.z, xb.w};
#pragma unroll
      for (int q = 0; q < 4; q++) {
        ha[q] = (_Float16)va[q];
        la[q] = (_Float16)(va[q] - (float)ha[q]);
        hb[q] = (_Float16)vb[q];
        lb[q] = (_Float16)(vb[q] - (float)hb[q]);
      }
      *(half2_t*)&As[0][sm][sk]      = *(half2_t*)&ha[0];
      *(half2_t*)&As[0][sm][sk + 2]  = *(half2_t*)&ha[2];
      *(half2_t*)&As[1][sm][sk]      = *(half2_t*)&la[0];
      *(half2_t*)&As[1][sm][sk + 2]  = *(half2_t*)&la[2];
      *(half2_t*)&As[0][sm][sk + 32] = *(half2_t*)&hb[0];
      *(half2_t*)&As[0][sm][sk + 34] = *(half2_t*)&hb[2];
      *(half2_t*)&As[1][sm][sk + 32] = *(half2_t*)&lb[0];
      *(half2_t*)&As[1][sm][sk + 34] = *(half2_t*)&lb[2];
    }
    __syncthreads();
#pragma unroll
    for (int ks = 0; ks < 2; ks++) {
      half8_t a_hi[2], a_lo[2];
#pragma unroll
      for (int fi = 0; fi < 2; fi++) {
        a_hi[fi] = *(const half8_t*)&As[0][16 * fi + n16][ks * 32 + 8 * g];
        a_lo[fi] = *(const half8_t*)&As[1][16 * fi + n16][ks * 32 + 8 * g];
      }
#pragma unroll
      for (int nj = 0; nj < 8; nj++) {
        int s = 128 * w + 16 * nj + n16;
        int sc = (s < 450) ? s : 449;
        half8_t bf = *(const half8_t*)(tabT + (size_t)sc * 1024 + k0 + ks * 32 + 8 * g);
#pragma unroll
        for (int fi = 0; fi < 2; fi++) {
          acc[fi][nj] = __builtin_amdgcn_mfma_f32_16x16x32_f16(a_hi[fi], bf, acc[fi][nj], 0, 0, 0);
          acc[fi][nj] = __builtin_amdgcn_mfma_f32_16x16x32_f16(a_lo[fi], bf, acc[fi][nj], 0, 0, 0);
        }
      }
    }
  }

#pragma unroll
  for (int fi = 0; fi < 2; fi++)
#pragma unroll
    for (int nj = 0; nj < 8; nj++) {
      int s = 128 * w + 16 * nj + n16;
      if (s < 450) {
#pragma unroll
        for (int q = 0; q < 4; q++) {
          int m = m0 + 16 * fi + 4 * g + q;
          C[(size_t)m * 450 + s] = acc[fi][nj][q];
        }
      }
    }
}

// ---------------- K2: fused network, 256 thr / 4 waves, fp16 residual in LDS, 3 blk/CU ----------------
struct NetArgs {
  const float *ccw, *ccb, *cclnw, *cclnb;
  const float *l1w[2], *l1b[2], *l2w[2], *l2b[2], *l3w[2], *l3b[2];
  const float *cb[2], *pb[2];
  const _Float16* wf;    // [2][16][64][8] conv A-fragments (global, L1-hot)
  const _Float16* pwf;   // [2][29][64][8] proj B-fragments
  char* rec;
};

__global__ __launch_bounds__(256, 3) void k_net(NetArgs a) {
  __shared__ _Float16 h_s[16][452];              // 14464 B (residual stream, fp16)
  __shared__ __align__(16) char regB[17024];     // xt(15872 B) + union{part(512 B)|ttT(1152 B)}
  __shared__ float red_s[16][2];                 // 128 B  -> total 31616 B

  const int tid = threadIdx.x;
  const int lane = tid & 63;
  const int w = tid >> 6;       // 0..3
  const int b = blockIdx.x;
  const int g = lane >> 4;
  const int n = lane & 15;

  _Float16* xt   = (_Float16*)regB;              // 496 rows x 16 halfs = 15872 B (swizzled)
  float*    part = (float*)(regB + 15872);       // [16][4][2] = 512 B, live P3->P4
  _Float16* ttT  = (_Float16*)(regB + 15872);    // [16][36] = 1152 B, live P7->P8
  float*    y0   = (float*)regB;                 // [8][452] = 14464 B, live pre-encoder

  // ---- stage h0, ChComb 1x1 conv + LN + GELU -> h_s ----
  const float* h0 = (const float*)(a.rec + (size_t)b * 14400);
  for (int idx = tid; idx < 3600; idx += 256) {
    int c = idx / 450;
    y0[c * 452 + (idx - c * 450)] = h0[idx];
  }
  __syncthreads();

#pragma unroll 1
  for (int rr = 0; rr < 4; rr++) {
    const int o = w * 4 + rr;
    float wv[8];
#pragma unroll
    for (int c = 0; c < 8; c++) wv[c] = a.ccw[o * 8 + c];
    const float cb0 = a.ccb[o];
    float vals[8];
    float sum = 0.f, sum2 = 0.f;
#pragma unroll
    for (int j = 0; j < 8; j++) {
      int s = lane + 64 * j;
      float v = 0.f;
      if (s < 450) {
        v = cb0;
#pragma unroll
        for (int c = 0; c < 8; c++) v = fmaf(y0[c * 452 + s], wv[c], v);
        sum += v; sum2 = fmaf(v, v, sum2);
      }
      vals[j] = v;
    }
    sum = wred64(sum); sum2 = wred64(sum2);
    float m = sum * (1.f / 450.f);
    float rs = rsqrtf(sum2 * (1.f / 450.f) - m * m + EPS_);
#pragma unroll
    for (int j = 0; j < 8; j++) {
      int s = lane + 64 * j;
      if (s < 450)
        h_s[o][s] = (_Float16)gelu_f((vals[j] - m) * rs * a.cclnw[s] + a.cclnb[s]);
    }
  }
  __syncthreads();

#pragma unroll 1
  for (int e = 0; e < 2; e++) {
    const float* l1w = a.l1w[e]; const float* l1b = a.l1b[e];
    const float* l2w = a.l2w[e]; const float* l2b = a.l2b[e];
    const float* l3w = a.l3w[e]; const float* l3b = a.l3b[e];
    const float* cbp = a.cb[e];
    const float* pb  = a.pb[e];
    const _Float16* wfe  = a.wf  + (size_t)e * 8192;   // 8192 halfs = 16384 B per encoder
    const _Float16* pwfe = a.pwf + (size_t)e * 14848;

    // ---- P1: Xt zero pads + LN1 stats ----
    for (int idx = tid; idx < 368; idx += 256) {
      int rr2 = idx >> 3;
      int rp = (rr2 < 15) ? rr2 : (450 + rr2);
      half2_t z; z[0] = (_Float16)0.f; z[1] = (_Float16)0.f;
      *(half2_t*)(xt + rp * 16 + (idx & 7) * 2) = z;
    }
#pragma unroll 1
    for (int rr = 0; rr < 4; rr++) {
      const int i = w * 4 + rr;
      float sum = 0.f, sum2 = 0.f;
#pragma unroll
      for (int j = 0; j < 8; j++) {
        int s = lane + 64 * j;
        if (s < 450) { float v = (float)h_s[i][s]; sum += v; sum2 = fmaf(v, v, sum2); }
      }
      sum = wred64(sum); sum2 = wred64(sum2);
      float m = sum * (1.f / 450.f);
      float rs = rsqrtf(sum2 * (1.f / 450.f) - m * m + EPS_);
      if (lane == 0) { red_s[i][0] = m; red_s[i][1] = rs; }
    }
    __syncthreads();

    // ---- P2: LN1 apply -> Xt (fp16, transposed, swizzled) ----
    for (int idx = tid; idx < 3600; idx += 256) {
      int s = idx >> 3, ip = idx & 7, i0 = ip * 2;
      float wv = l1w[s], bv = l1b[s];
      float x0 = ((float)h_s[i0][s]     - red_s[i0][0])     * red_s[i0][1]     * wv + bv;
      float x1 = ((float)h_s[i0 + 1][s] - red_s[i0 + 1][0]) * red_s[i0 + 1][1] * wv + bv;
      int rp = s + 15;
      int hh = (ip >> 2) ^ ((rp >> 2) & 1);
      half2_t pk; pk[0] = (_Float16)x0; pk[1] = (_Float16)x1;
      *(half2_t*)(xt + rp * 16 + hh * 8 + (i0 & 7)) = pk;
    }
    __syncthreads();

    // ---- P3: conv via MFMA 16x16x32 f16 (8 tiles/wave); A-frags direct from global ----
    const int hh0 = g & 1;
    const int dt = g >> 1;
    f32x4_t acc[8];
#pragma unroll 1
    for (int pp = 0; pp < 4; pp++) {
      f32x4_t aA = {0.f, 0.f, 0.f, 0.f};
      f32x4_t aB = {0.f, 0.f, 0.f, 0.f};
      int tA = w + 4 * (2 * pp);     if (tA > 28) tA = 28;
      int tB = w + 4 * (2 * pp + 1); if (tB > 28) tB = 28;
      int rbA = tA * 16 + n + dt;
      int rbB = tB * 16 + n + dt;
#pragma unroll
      for (int t = 0; t < 16; t++) {
        half8_t af = *(const half8_t*)(wfe + ((t << 6) + lane) * 8);
        int rA = rbA + 2 * t;
        int rB = rbB + 2 * t;
        half8_t bA = *(const half8_t*)(xt + rA * 16 + ((hh0 ^ ((rA >> 2) & 1)) << 3));
        half8_t bB = *(const half8_t*)(xt + rB * 16 + ((hh0 ^ ((rB >> 2) & 1)) << 3));
        aA = __builtin_amdgcn_mfma_f32_16x16x32_f16(af, bA, aA, 0, 0, 0);
        aB = __builtin_amdgcn_mfma_f32_16x16x32_f16(af, bB, aB, 0, 0, 0);
      }
      acc[2 * pp] = aA; acc[2 * pp + 1] = aB;
    }

    // raw partial sums (cb folded in at P4); part does not alias xt -> no extra barrier
    float s1[4] = {0.f, 0.f, 0.f, 0.f}, s2[4] = {0.f, 0.f, 0.f, 0.f};
#pragma unroll
    for (int tt = 0; tt < 8; tt++) {
      int t0 = w + 4 * tt;
      if (t0 < 29) {
        int s = t0 * 16 + n;
        if (s < 450) {
#pragma unroll
          for (int q = 0; q < 4; q++) {
            float v = acc[tt][q];
            s1[q] += v; s2[q] = fmaf(v, v, s2[q]);
          }
        }
      }
    }
#pragma unroll
    for (int m = 1; m < 16; m <<= 1) {
#pragma unroll
      for (int q = 0; q < 4; q++) {
        s1[q] += __shfl_xor(s1[q], m, 64);
        s2[q] += __shfl_xor(s2[q], m, 64);
      }
    }
    if (n == 0) {
#pragma unroll
      for (int q = 0; q < 4; q++) {
        part[((4 * g + q) * 4 + w) * 2 + 0] = s1[q];
        part[((4 * g + q) * 4 + w) * 2 + 1] = s2[q];
      }
    }
    __syncthreads();

    // ---- P4: finalize LN2 stats (fold conv bias here) ----
    if (tid < 16) {
      float u1 = 0.f, u2 = 0.f;
#pragma unroll
      for (int ww = 0; ww < 4; ww++) {
        u1 += part[(tid * 4 + ww) * 2 + 0];
        u2 += part[(tid * 4 + ww) * 2 + 1];
      }
      float cb0 = cbp[tid];
      float u2p = u2 + 2.f * cb0 * u1 + 450.f * cb0 * cb0;
      float u1p = u1 + 450.f * cb0;
      float m = u1p * (1.f / 450.f);
      float rs = rsqrtf(u2p * (1.f / 450.f) - m * m + EPS_);
      red_s[tid][0] = m; red_s[tid][1] = rs;
    }
    __syncthreads();

    // ---- P5: LN2 + GELU + residual -> h_s (fp16 accumulate) ----
    {
      float mq[4], rq[4], cbq[4];
#pragma unroll
      for (int q = 0; q < 4; q++) {
        mq[q] = red_s[4 * g + q][0]; rq[q] = red_s[4 * g + q][1];
        cbq[q] = cbp[4 * g + q];
      }
#pragma unroll
      for (int tt = 0; tt < 8; tt++) {
        int t0 = w + 4 * tt;
        if (t0 < 29) {
          int s = t0 * 16 + n;
          if (s < 450) {
            float wv = l2w[s], bv = l2b[s];
#pragma unroll
            for (int q = 0; q < 4; q++) {
              int o = 4 * g + q;
              float v = acc[tt][q] + cbq[q];
              h_s[o][s] = (_Float16)((float)h_s[o][s] +
                                     gelu_f((v - mq[q]) * rq[q] * wv + bv));
            }
          }
        }
      }
    }
    __syncthreads();

    // ---- P6: LN3 stats ----
#pragma unroll 1
    for (int rr = 0; rr < 4; rr++) {
      const int c = w * 4 + rr;
      float sum = 0.f, sum2 = 0.f;
#pragma unroll
      for (int j = 0; j < 8; j++) {
        int s = lane + 64 * j;
        if (s < 450) { float v = (float)h_s[c][s]; sum += v; sum2 = fmaf(v, v, sum2); }
      }
      sum = wred64(sum); sum2 = wred64(sum2);
      float m = sum * (1.f / 450.f);
      float rs = rsqrtf(sum2 * (1.f / 450.f) - m * m + EPS_);
      if (lane == 0) { red_s[c][0] = m; red_s[c][1] = rs; }
    }
    __syncthreads();

    // ---- P7: ttT[i][c] = fp16 LN3(h)[c][i], zero pad c in [16,32) ----
    {
      int c = tid >> 4, i = tid & 15;
      float v = ((float)h_s[c][i] - red_s[c][0]) * red_s[c][1] * l3w[i] + l3b[i];
      ttT[i * 36 + c] = (_Float16)v;
      ttT[i * 36 + 16 + c] = (_Float16)0.f;
    }
    __syncthreads();

    // ---- P8: proj via MFMA: h[i][s] += sum_c t2[c][i]*pw[s][c] + pb[s] ----
#pragma unroll
    for (int p = 0; p < 8; p++) {
      int T = w + 4 * p;
      if (T < 29) {
        half8_t afr = *(const half8_t*)(ttT + n * 36 + 8 * g);
        half8_t bfr = *(const half8_t*)(pwfe + (size_t)T * 512 + lane * 8);
        f32x4_t d = {0.f, 0.f, 0.f, 0.f};
        d = __builtin_amdgcn_mfma_f32_16x16x32_f16(afr, bfr, d, 0, 0, 0);
        int s = 16 * T + n;
        if (s < 450) {
          float pbv = pb[s];
#pragma unroll
          for (int q = 0; q < 4; q++) {
            int o = 4 * g + q;
            h_s[o][s] = (_Float16)((float)h_s[o][s] + d[q] + pbv);
          }
        }
      }
    }
    __syncthreads();
  }

  // ---- write hfinal as bf16 over own record ----
  __hip_bfloat16* hf = (__hip_bfloat16*)(a.rec + (size_t)b * 14400);
  for (int idx = tid; idx < 7200; idx += 256) {
    int c = idx / 450;
    hf[idx] = __float2bfloat16((float)h_s[c][idx - c * 450]);
  }
}

// ---------------- K3: MLP head via bf16 MFMA, 4-way K-split, 256 thr ----------------
struct MlpArgs {
  const char* rec;
  const __hip_bfloat16* w1b;
  const float *b1, *lnw, *lnb, *w2, *b2;
  float* out;
};

__global__ __launch_bounds__(256) void k_mlp(MlpArgs a) {
  __shared__ float w2s[12][76];
  __shared__ float b1s[72], lnws[72], lnbs[72];
  __shared__ float accs[4][64][20];   // per-wave K-partials, 20480 B

  const int tid = threadIdx.x;
  const int wv = tid >> 6;
  const int l = tid & 63;
  const int g = l >> 4, n16 = l & 15;
  const int m0 = blockIdx.x * 16;

  for (int i = tid; i < 864; i += 256) { int c = i / 72, j = i - c * 72; w2s[c][j] = a.w2[i]; }
  for (int i = tid; i < 72; i += 256) { b1s[i] = a.b1[i]; lnws[i] = a.lnw[i]; lnbs[i] = a.lnb[i]; }

  const unsigned short* arow =
      (const unsigned short*)(a.rec + (size_t)(m0 + n16) * 14400) + 8 * g;
  const unsigned short* bp[5];
#pragma unroll
  for (int nt = 0; nt < 5; nt++) {
    int r = 16 * nt + n16; if (r > 71) r = 71;
    bp[nt] = (const unsigned short*)a.w1b + (size_t)r * 7200 + 8 * g;
  }

  f32x4_t acc[5];
#pragma unroll
  for (int nt = 0; nt < 5; nt++) acc[nt] = (f32x4_t){0.f, 0.f, 0.f, 0.f};

  const int kt0 = wv * 57;
  const int kt1 = (kt0 + 57 < 225) ? (kt0 + 57) : 225;
#pragma unroll 3
  for (int kt = kt0; kt < kt1; ++kt) {
    bf16x8_t af = *(const bf16x8_t*)(arow + 32 * kt);
#pragma unroll
    for (int nt = 0; nt < 5; nt++) {
      bf16x8_t bf = *(const bf16x8_t*)(bp[nt] + 32 * kt);
      acc[nt] = __builtin_amdgcn_mfma_f32_16x16x32_bf16(af, bf, acc[nt], 0, 0, 0);
    }
  }

#pragma unroll
  for (int nt = 0; nt < 5; nt++)
#pragma unroll
    for (int q = 0; q < 4; q++) accs[wv][l][nt * 4 + q] = acc[nt][q];
  __syncthreads();

  if (wv == 0) {
    // sum K-partials
#pragma unroll
    for (int nt = 0; nt < 5; nt++)
#pragma unroll
      for (int q = 0; q < 4; q++)
        acc[nt][q] = accs[0][l][nt * 4 + q] + accs[1][l][nt * 4 + q] +
                     accs[2][l][nt * 4 + q] + accs[3][l][nt * 4 + q];

    // epilogue: +b1, LN(72), GELU, @w2.T + b2
    float yv[5][4];
    float sum[4] = {0.f, 0.f, 0.f, 0.f}, sum2[4] = {0.f, 0.f, 0.f, 0.f};
#pragma unroll
    for (int nt = 0; nt < 5; nt++) {
      int j = 16 * nt + n16;
      bool val = (j < 72);
#pragma unroll
      for (int q = 0; q < 4; q++) {
        float v = val ? (acc[nt][q] + b1s[j]) : 0.f;
        yv[nt][q] = v;
        sum[q] += v; sum2[q] = fmaf(v, v, sum2[q]);
      }
    }
#pragma unroll
    for (int m = 1; m < 16; m <<= 1) {
#pragma unroll
      for (int q = 0; q < 4; q++) {
        sum[q] += __shfl_xor(sum[q], m, 64);
        sum2[q] += __shfl_xor(sum2[q], m, 64);
      }
    }
    float mm[4], rs[4];
#pragma unroll
    for (int q = 0; q < 4; q++) {
      mm[q] = sum[q] * (1.f / 72.f);
      rs[q] = rsqrtf(sum2[q] * (1.f / 72.f) - mm[q] * mm[q] + EPS_);
    }

    float p[4][12];
#pragma unroll
    for (int q = 0; q < 4; q++)
#pragma unroll
      for (int c = 0; c < 12; c++) p[q][c] = 0.f;

#pragma unroll
    for (int nt = 0; nt < 5; nt++) {
      int j = 16 * nt + n16;
      if (j < 72) {
        float lw = lnws[j], lb = lnbs[j];
#pragma unroll
        for (int q = 0; q < 4; q++) {
          float y2 = gelu_f((yv[nt][q] - mm[q]) * rs[q] * lw + lb);
#pragma unroll
          for (int c = 0; c < 12; c++) p[q][c] = fmaf(y2, w2s[c][j], p[q][c]);
        }
      }
    }
#pragma unroll
    for (int m = 1; m < 16; m <<= 1) {
#pragma unroll
      for (int q = 0; q < 4; q++)
#pragma unroll
        for (int c = 0; c < 12; c++) p[q][c] += __shfl_xor(p[q][c], m, 64);
    }

    if (n16 == 0) {
#pragma unroll
      for (int q = 0; q < 4; q++) {
        int m = m0 + 4 * g + q;
        float4 o0 = make_float4(p[q][0] + a.b2[0], p[q][1] + a.b2[1], p[q][2] + a.b2[2], p[q][3] + a.b2[3]);
        float4 o1 = make_float4(p[q][4] + a.b2[4], p[q][5] + a.b2[5], p[q][6] + a.b2[6], p[q][7] + a.b2[7]);
        float4 o2 = make_float4(p[q][8] + a.b2[8], p[q][9] + a.b2[9], p[q][10] + a.b2[10], p[q][11] + a.b2[11]);
        *(float4*)&a.out[(size_t)m * 12]     = o0;
        *(float4*)&a.out[(size_t)m * 12 + 4] = o1;
        *(float4*)&a.out[(size_t)m * 12 + 8] = o2;
      }
    }
  }
}

// ---------------- launch ----------------
extern "C" void kernel_launch(void* const* d_in, const int* in_sizes, int n_in,
                              void* d_out, int out_size, void* d_ws, size_t ws_size,
                              hipStream_t stream) {
  const float* x = (const float*)d_in[0];

  _Float16* tabT = (_Float16*)d_ws;                              // 450*1024*2 = 921600 B
  _Float16* wf  = (_Float16*)((char*)d_ws + 921600);             // 65536 B
  _Float16* pwf = (_Float16*)((char*)d_ws + 987136);             // 59392 B
  __hip_bfloat16* w1b = (__hip_bfloat16*)((char*)d_ws + 1046528); // 1036800 B -> ends 2083328
  char* rec = (char*)d_ws + (size_t)(2 * 1024 * 1024);           // 8192 * 14400 B

  k_table<<<1800, 256, 0, stream>>>(tabT);
  k_prep<<<2269, 256, 0, stream>>>((const float*)d_in[11], (const float*)d_in[21],
                                   (const float*)d_in[13], (const float*)d_in[23],
                                   (const float*)d_in[25], wf, pwf, w1b);
  k_dft<<<2048, 256, 0, stream>>>(x, tabT, (float*)rec);

  NetArgs na;
  na.ccw = (const float*)d_in[1];
  na.ccb = (const float*)d_in[2];
  na.cclnw = (const float*)d_in[3];
  na.cclnb = (const float*)d_in[4];
  for (int e = 0; e < 2; e++) {
    int o = 5 + e * 10;
    na.l1w[e] = (const float*)d_in[o + 0];
    na.l1b[e] = (const float*)d_in[o + 1];
    na.l2w[e] = (const float*)d_in[o + 2];
    na.l2b[e] = (const float*)d_in[o + 3];
    na.l3w[e] = (const float*)d_in[o + 4];
    na.l3b[e] = (const float*)d_in[o + 5];
    na.cb[e]  = (const float*)d_in[o + 7];
    na.pb[e]  = (const float*)d_in[o + 9];
  }
  na.wf = wf;
  na.pwf = pwf;
  na.rec = rec;
  k_net<<<8192, 256, 0, stream>>>(na);

  MlpArgs ma;
  ma.rec = rec;
  ma.w1b = w1b;
  ma.b1 = (const float*)d_in[26];
  ma.lnw = (const float*)d_in[27];
  ma.lnb = (const float*)d_in[28];
  ma.w2 = (const float*)d_in[29];
  ma.b2 = (const float*)d_in[30];
  ma.out = (float*)d_out;
  k_mlp<<<512, 256, 0, stream>>>(ma);
}

// Round 17
// 968.274 us; speedup vs baseline: 1.2359x; 1.0163x over previous
//
#include <hip/hip_runtime.h>
#include <hip/hip_bf16.h>
#include <math.h>

#define EPS_ 1e-5f

typedef _Float16 half8_t __attribute__((ext_vector_type(8)));
typedef _Float16 half2_t __attribute__((ext_vector_type(2)));
typedef float f32x4_t __attribute__((ext_vector_type(4)));
typedef short bf16x8_t __attribute__((ext_vector_type(8)));

// fast GELU (tanh form), |err| vs exact erf-GELU <~4e-4; clamped for inf-safety
__device__ __forceinline__ float gelu_f(float x) {
  float u2 = x * fmaf(0.0713548162f, x * x, 1.5957691216f);
  u2 = fminf(u2, 80.f);
  float e = __expf(u2);
  return x - x / (1.f + e);
}

__device__ __forceinline__ float wred64(float v) {
#pragma unroll
  for (int m = 32; m > 0; m >>= 1) v += __shfl_xor(v, m, 64);
  return v;
}

// ---------------- K0: fp16 transposed DFT table tabT[s][t], s in [0,450) ----------------
__global__ void k_table(_Float16* __restrict__ tabT) {
  int idx = blockIdx.x * 256 + threadIdx.x;
  if (idx >= 450 * 1024) return;
  int s = idx >> 10;
  int t = idx & 1023;
  int f = (s < 225) ? (32 + s) : (s - 225 + 32);
  int ph = (f * t) & 1023;
  float ang = (float)ph * (6.2831853071795864769e0f / 1024.0f);
  float v = ((s < 225) ? cosf(ang) : -sinf(ang)) * (1.0f / 1024.0f);
  tabT[idx] = (_Float16)v;
}

// ---------------- K0b: pack conv + proj weights (fp16 fragments) + w1 bf16 copy ----------------
__global__ void k_prep(const float* __restrict__ cw0, const float* __restrict__ cw1,
                       const float* __restrict__ pw0, const float* __restrict__ pw1,
                       const float* __restrict__ w1,
                       _Float16* __restrict__ wf, _Float16* __restrict__ pwf,
                       __hip_bfloat16* __restrict__ w1b) {
  int idx = blockIdx.x * 256 + threadIdx.x;
  if (idx < 32768) {
    int j = idx & 7;
    int l = (idx >> 3) & 63;
    int t = (idx >> 9) & 15;
    int e = idx >> 13;
    int g = l >> 4, o = l & 15;
    int i = 8 * (g & 1) + j;
    int k = 2 * t + (g >> 1);
    const float* cw = e ? cw1 : cw0;
    float v = (k < 31) ? cw[(o * 16 + i) * 31 + k] : 0.f;
    wf[idx] = (_Float16)v;
  } else if (idx < 62464) {
    int idx2 = idx - 32768;
    int e = idx2 / 14848;
    int r = idx2 - e * 14848;
    int T = r >> 9;
    int l = (r >> 3) & 63;
    int j = r & 7;
    int g = l >> 4;
    int c = 8 * g + j;
    int s = 16 * T + (l & 15);
    const float* pws = e ? pw1 : pw0;
    float v = (c < 16 && s < 450) ? pws[s * 16 + c] : 0.f;
    pwf[idx2] = (_Float16)v;
  } else if (idx < 62464 + 518400) {
    int idx2 = idx - 62464;
    w1b[idx2] = __float2bfloat16(w1[idx2]);
  }
}

// ---------------- K1: DFT GEMM via fp16 MFMA (single-precision fp16 x) ----------------
__global__ __launch_bounds__(256) void k_dft(const float* __restrict__ X,
                                             const _Float16* __restrict__ tabT,
                                             float* __restrict__ C) {
  __shared__ _Float16 As[32][72];   // [m][k] pitch 72 halfs

  const int tid = threadIdx.x;
  const int l = tid & 63;
  const int w = tid >> 6;        // wave -> n-strip base 128*w
  const int g = l >> 4;
  const int n16 = l & 15;
  const int m0 = blockIdx.x * 32;

  const int sm = tid >> 3;          // staging row 0..31
  const int sk = (tid & 7) * 4;     // staging k 0..28

  f32x4_t acc[2][8];
#pragma unroll
  for (int fi = 0; fi < 2; fi++)
#pragma unroll
    for (int nj = 0; nj < 8; nj++) acc[fi][nj] = (f32x4_t){0.f, 0.f, 0.f, 0.f};

  const float* xrow = X + (size_t)(m0 + sm) * 1024 + sk;

  for (int k0 = 0; k0 < 1024; k0 += 64) {
    float4 xa = *(const float4*)(xrow + k0);
    float4 xb = *(const float4*)(xrow + k0 + 32);
    __syncthreads();
    {
      _Float16 ha[4], hb[4];
      ha[0] = (_Float16)xa.x; ha[1] = (_Float16)xa.y;
      ha[2] = (_Float16)xa.z; ha[3] = (_Float16)xa.w;
      hb[0] = (_Float16)xb.x; hb[1] = (_Float16)xb.y;
      hb[2] = (_Float16)xb.z; hb[3] = (_Float16)xb.w;
      *(half2_t*)&As[sm][sk]      = *(half2_t*)&ha[0];
      *(half2_t*)&As[sm][sk + 2]  = *(half2_t*)&ha[2];
      *(half2_t*)&As[sm][sk + 32] = *(half2_t*)&hb[0];
      *(half2_t*)&As[sm][sk + 34] = *(half2_t*)&hb[2];
    }
    __syncthreads();
#pragma unroll
    for (int ks = 0; ks < 2; ks++) {
      half8_t av[2];
#pragma unroll
      for (int fi = 0; fi < 2; fi++)
        av[fi] = *(const half8_t*)&As[16 * fi + n16][ks * 32 + 8 * g];
#pragma unroll
      for (int nj = 0; nj < 8; nj++) {
        int s = 128 * w + 16 * nj + n16;
        int sc = (s < 450) ? s : 449;
        half8_t bf = *(const half8_t*)(tabT + (size_t)sc * 1024 + k0 + ks * 32 + 8 * g);
#pragma unroll
        for (int fi = 0; fi < 2; fi++)
          acc[fi][nj] = __builtin_amdgcn_mfma_f32_16x16x32_f16(av[fi], bf, acc[fi][nj], 0, 0, 0);
      }
    }
  }

#pragma unroll
  for (int fi = 0; fi < 2; fi++)
#pragma unroll
    for (int nj = 0; nj < 8; nj++) {
      int s = 128 * w + 16 * nj + n16;
      if (s < 450) {
#pragma unroll
        for (int q = 0; q < 4; q++) {
          int m = m0 + 16 * fi + 4 * g + q;
          C[(size_t)m * 450 + s] = acc[fi][nj][q];
        }
      }
    }
}

// ---------------- K2: fused network, 256 thr / 4 waves, fp16 residual in LDS, 3 blk/CU ----------------
struct NetArgs {
  const float *ccw, *ccb, *cclnw, *cclnb;
  const float *l1w[2], *l1b[2], *l2w[2], *l2b[2], *l3w[2], *l3b[2];
  const float *cb[2], *pb[2];
  const _Float16* wf;    // [2][16][64][8] conv A-fragments (global, L1-hot)
  const _Float16* pwf;   // [2][29][64][8] proj B-fragments
  char* rec;
};

__global__ __launch_bounds__(256, 3) void k_net(NetArgs a) {
  __shared__ _Float16 h_s[16][452];              // 14464 B (residual stream, fp16)
  __shared__ __align__(16) char regB[17024];     // xt(15872 B) + union{part(512 B)|ttT(1152 B)}
  __shared__ float red_s[16][2];                 // 128 B  -> total 31616 B

  const int tid = threadIdx.x;
  const int lane = tid & 63;
  const int w = tid >> 6;       // 0..3
  const int b = blockIdx.x;
  const int g = lane >> 4;
  const int n = lane & 15;

  _Float16* xt   = (_Float16*)regB;              // 496 rows x 16 halfs = 15872 B (swizzled)
  float*    part = (float*)(regB + 15872);       // [16][4][2] = 512 B, live P3->P4
  _Float16* ttT  = (_Float16*)(regB + 15872);    // [16][36] = 1152 B, live P7->P8
  float*    y0   = (float*)regB;                 // [8][452] = 14464 B, live pre-encoder

  // ---- stage h0, ChComb 1x1 conv + LN + GELU -> h_s ----
  const float* h0 = (const float*)(a.rec + (size_t)b * 14400);
  for (int idx = tid; idx < 3600; idx += 256) {
    int c = idx / 450;
    y0[c * 452 + (idx - c * 450)] = h0[idx];
  }
  __syncthreads();

#pragma unroll 1
  for (int rr = 0; rr < 4; rr++) {
    const int o = w * 4 + rr;
    float wv[8];
#pragma unroll
    for (int c = 0; c < 8; c++) wv[c] = a.ccw[o * 8 + c];
    const float cb0 = a.ccb[o];
    float vals[8];
    float sum = 0.f, sum2 = 0.f;
#pragma unroll
    for (int j = 0; j < 8; j++) {
      int s = lane + 64 * j;
      float v = 0.f;
      if (s < 450) {
        v = cb0;
#pragma unroll
        for (int c = 0; c < 8; c++) v = fmaf(y0[c * 452 + s], wv[c], v);
        sum += v; sum2 = fmaf(v, v, sum2);
      }
      vals[j] = v;
    }
    sum = wred64(sum); sum2 = wred64(sum2);
    float m = sum * (1.f / 450.f);
    float rs = rsqrtf(sum2 * (1.f / 450.f) - m * m + EPS_);
#pragma unroll
    for (int j = 0; j < 8; j++) {
      int s = lane + 64 * j;
      if (s < 450)
        h_s[o][s] = (_Float16)gelu_f((vals[j] - m) * rs * a.cclnw[s] + a.cclnb[s]);
    }
  }
  __syncthreads();

#pragma unroll 1
  for (int e = 0; e < 2; e++) {
    const float* l1w = a.l1w[e]; const float* l1b = a.l1b[e];
    const float* l2w = a.l2w[e]; const float* l2b = a.l2b[e];
    const float* l3w = a.l3w[e]; const float* l3b = a.l3b[e];
    const float* cbp = a.cb[e];
    const float* pb  = a.pb[e];
    const _Float16* wfe  = a.wf  + (size_t)e * 8192;   // 8192 halfs = 16384 B per encoder
    const _Float16* pwfe = a.pwf + (size_t)e * 14848;

    // ---- P1: Xt zero pads + LN1 stats ----
    for (int idx = tid; idx < 368; idx += 256) {
      int rr2 = idx >> 3;
      int rp = (rr2 < 15) ? rr2 : (450 + rr2);
      half2_t z; z[0] = (_Float16)0.f; z[1] = (_Float16)0.f;
      *(half2_t*)(xt + rp * 16 + (idx & 7) * 2) = z;
    }
#pragma unroll 1
    for (int rr = 0; rr < 4; rr++) {
      const int i = w * 4 + rr;
      float sum = 0.f, sum2 = 0.f;
#pragma unroll
      for (int j = 0; j < 8; j++) {
        int s = lane + 64 * j;
        if (s < 450) { float v = (float)h_s[i][s]; sum += v; sum2 = fmaf(v, v, sum2); }
      }
      sum = wred64(sum); sum2 = wred64(sum2);
      float m = sum * (1.f / 450.f);
      float rs = rsqrtf(sum2 * (1.f / 450.f) - m * m + EPS_);
      if (lane == 0) { red_s[i][0] = m; red_s[i][1] = rs; }
    }
    __syncthreads();

    // ---- P2: LN1 apply -> Xt (fp16, transposed, swizzled) ----
    for (int idx = tid; idx < 3600; idx += 256) {
      int s = idx >> 3, ip = idx & 7, i0 = ip * 2;
      float wv = l1w[s], bv = l1b[s];
      float x0 = ((float)h_s[i0][s]     - red_s[i0][0])     * red_s[i0][1]     * wv + bv;
      float x1 = ((float)h_s[i0 + 1][s] - red_s[i0 + 1][0]) * red_s[i0 + 1][1] * wv + bv;
      int rp = s + 15;
      int hh = (ip >> 2) ^ ((rp >> 2) & 1);
      half2_t pk; pk[0] = (_Float16)x0; pk[1] = (_Float16)x1;
      *(half2_t*)(xt + rp * 16 + hh * 8 + (i0 & 7)) = pk;
    }
    __syncthreads();

    // ---- P3: conv via MFMA 16x16x32 f16 (8 tiles/wave); A-frags direct from global ----
    const int hh0 = g & 1;
    const int dt = g >> 1;
    f32x4_t acc[8];
#pragma unroll 1
    for (int pp = 0; pp < 4; pp++) {
      f32x4_t aA = {0.f, 0.f, 0.f, 0.f};
      f32x4_t aB = {0.f, 0.f, 0.f, 0.f};
      int tA = w + 4 * (2 * pp);     if (tA > 28) tA = 28;
      int tB = w + 4 * (2 * pp + 1); if (tB > 28) tB = 28;
      int rbA = tA * 16 + n + dt;
      int rbB = tB * 16 + n + dt;
#pragma unroll
      for (int t = 0; t < 16; t++) {
        half8_t af = *(const half8_t*)(wfe + ((t << 6) + lane) * 8);
        int rA = rbA + 2 * t;
        int rB = rbB + 2 * t;
        half8_t bA = *(const half8_t*)(xt + rA * 16 + ((hh0 ^ ((rA >> 2) & 1)) << 3));
        half8_t bB = *(const half8_t*)(xt + rB * 16 + ((hh0 ^ ((rB >> 2) & 1)) << 3));
        aA = __builtin_amdgcn_mfma_f32_16x16x32_f16(af, bA, aA, 0, 0, 0);
        aB = __builtin_amdgcn_mfma_f32_16x16x32_f16(af, bB, aB, 0, 0, 0);
      }
      acc[2 * pp] = aA; acc[2 * pp + 1] = aB;
    }

    // raw partial sums (cb folded in at P4); part does not alias xt -> no extra barrier
    float s1[4] = {0.f, 0.f, 0.f, 0.f}, s2[4] = {0.f, 0.f, 0.f, 0.f};
#pragma unroll
    for (int tt = 0; tt < 8; tt++) {
      int t0 = w + 4 * tt;
      if (t0 < 29) {
        int s = t0 * 16 + n;
        if (s < 450) {
#pragma unroll
          for (int q = 0; q < 4; q++) {
            float v = acc[tt][q];
            s1[q] += v; s2[q] = fmaf(v, v, s2[q]);
          }
        }
      }
    }
#pragma unroll
    for (int m = 1; m < 16; m <<= 1) {
#pragma unroll
      for (int q = 0; q < 4; q++) {
        s1[q] += __shfl_xor(s1[q], m, 64);
        s2[q] += __shfl_xor(s2[q], m, 64);
      }
    }
    if (n == 0) {
#pragma unroll
      for (int q = 0; q < 4; q++) {
        part[((4 * g + q) * 4 + w) * 2 + 0] = s1[q];
        part[((4 * g + q) * 4 + w) * 2 + 1] = s2[q];
      }
    }
    __syncthreads();

    // ---- P4: finalize LN2 stats (fold conv bias here) ----
    if (tid < 16) {
      float u1 = 0.f, u2 = 0.f;
#pragma unroll
      for (int ww = 0; ww < 4; ww++) {
        u1 += part[(tid * 4 + ww) * 2 + 0];
        u2 += part[(tid * 4 + ww) * 2 + 1];
      }
      float cb0 = cbp[tid];
      float u2p = u2 + 2.f * cb0 * u1 + 450.f * cb0 * cb0;
      float u1p = u1 + 450.f * cb0;
      float m = u1p * (1.f / 450.f);
      float rs = rsqrtf(u2p * (1.f / 450.f) - m * m + EPS_);
      red_s[tid][0] = m; red_s[tid][1] = rs;
    }
    __syncthreads();

    // ---- P5: LN2 + GELU + residual -> h_s (fp16 accumulate) ----
    {
      float mq[4], rq[4], cbq[4];
#pragma unroll
      for (int q = 0; q < 4; q++) {
        mq[q] = red_s[4 * g + q][0]; rq[q] = red_s[4 * g + q][1];
        cbq[q] = cbp[4 * g + q];
      }
#pragma unroll
      for (int tt = 0; tt < 8; tt++) {
        int t0 = w + 4 * tt;
        if (t0 < 29) {
          int s = t0 * 16 + n;
          if (s < 450) {
            float wv = l2w[s], bv = l2b[s];
#pragma unroll
            for (int q = 0; q < 4; q++) {
              int o = 4 * g + q;
              float v = acc[tt][q] + cbq[q];
              h_s[o][s] = (_Float16)((float)h_s[o][s] +
                                     gelu_f((v - mq[q]) * rq[q] * wv + bv));
            }
          }
        }
      }
    }
    __syncthreads();

    // ---- P6: LN3 stats ----
#pragma unroll 1
    for (int rr = 0; rr < 4; rr++) {
      const int c = w * 4 + rr;
      float sum = 0.f, sum2 = 0.f;
#pragma unroll
      for (int j = 0; j < 8; j++) {
        int s = lane + 64 * j;
        if (s < 450) { float v = (float)h_s[c][s]; sum += v; sum2 = fmaf(v, v, sum2); }
      }
      sum = wred64(sum); sum2 = wred64(sum2);
      float m = sum * (1.f / 450.f);
      float rs = rsqrtf(sum2 * (1.f / 450.f) - m * m + EPS_);
      if (lane == 0) { red_s[c][0] = m; red_s[c][1] = rs; }
    }
    __syncthreads();

    // ---- P7: ttT[i][c] = fp16 LN3(h)[c][i], zero pad c in [16,32) ----
    {
      int c = tid >> 4, i = tid & 15;
      float v = ((float)h_s[c][i] - red_s[c][0]) * red_s[c][1] * l3w[i] + l3b[i];
      ttT[i * 36 + c] = (_Float16)v;
      ttT[i * 36 + 16 + c] = (_Float16)0.f;
    }
    __syncthreads();

    // ---- P8: proj via MFMA: h[i][s] += sum_c t2[c][i]*pw[s][c] + pb[s] ----
#pragma unroll
    for (int p = 0; p < 8; p++) {
      int T = w + 4 * p;
      if (T < 29) {
        half8_t afr = *(const half8_t*)(ttT + n * 36 + 8 * g);
        half8_t bfr = *(const half8_t*)(pwfe + (size_t)T * 512 + lane * 8);
        f32x4_t d = {0.f, 0.f, 0.f, 0.f};
        d = __builtin_amdgcn_mfma_f32_16x16x32_f16(afr, bfr, d, 0, 0, 0);
        int s = 16 * T + n;
        if (s < 450) {
          float pbv = pb[s];
#pragma unroll
          for (int q = 0; q < 4; q++) {
            int o = 4 * g + q;
            h_s[o][s] = (_Float16)((float)h_s[o][s] + d[q] + pbv);
          }
        }
      }
    }
    __syncthreads();
  }

  // ---- write hfinal as bf16 over own record ----
  __hip_bfloat16* hf = (__hip_bfloat16*)(a.rec + (size_t)b * 14400);
  for (int idx = tid; idx < 7200; idx += 256) {
    int c = idx / 450;
    hf[idx] = __float2bfloat16((float)h_s[c][idx - c * 450]);
  }
}

// ---------------- K3: MLP head via bf16 MFMA, 4-way K-split, 256 thr ----------------
struct MlpArgs {
  const char* rec;
  const __hip_bfloat16* w1b;
  const float *b1, *lnw, *lnb, *w2, *b2;
  float* out;
};

__global__ __launch_bounds__(256) void k_mlp(MlpArgs a) {
  __shared__ float w2s[12][76];
  __shared__ float b1s[72], lnws[72], lnbs[72];
  __shared__ float accs[4][64][20];   // per-wave K-partials, 20480 B

  const int tid = threadIdx.x;
  const int wv = tid >> 6;
  const int l = tid & 63;
  const int g = l >> 4, n16 = l & 15;
  const int m0 = blockIdx.x * 16;

  for (int i = tid; i < 864; i += 256) { int c = i / 72, j = i - c * 72; w2s[c][j] = a.w2[i]; }
  for (int i = tid; i < 72; i += 256) { b1s[i] = a.b1[i]; lnws[i] = a.lnw[i]; lnbs[i] = a.lnb[i]; }

  const unsigned short* arow =
      (const unsigned short*)(a.rec + (size_t)(m0 + n16) * 14400) + 8 * g;
  const unsigned short* bp[5];
#pragma unroll
  for (int nt = 0; nt < 5; nt++) {
    int r = 16 * nt + n16; if (r > 71) r = 71;
    bp[nt] = (const unsigned short*)a.w1b + (size_t)r * 7200 + 8 * g;
  }

  f32x4_t acc[5];
#pragma unroll
  for (int nt = 0; nt < 5; nt++) acc[nt] = (f32x4_t){0.f, 0.f, 0.f, 0.f};

  const int kt0 = wv * 57;
  const int kt1 = (kt0 + 57 < 225) ? (kt0 + 57) : 225;
#pragma unroll 3
  for (int kt = kt0; kt < kt1; ++kt) {
    bf16x8_t af = *(const bf16x8_t*)(arow + 32 * kt);
#pragma unroll
    for (int nt = 0; nt < 5; nt++) {
      bf16x8_t bf = *(const bf16x8_t*)(bp[nt] + 32 * kt);
      acc[nt] = __builtin_amdgcn_mfma_f32_16x16x32_bf16(af, bf, acc[nt], 0, 0, 0);
    }
  }

#pragma unroll
  for (int nt = 0; nt < 5; nt++)
#pragma unroll
    for (int q = 0; q < 4; q++) accs[wv][l][nt * 4 + q] = acc[nt][q];
  __syncthreads();

  if (wv == 0) {
    // sum K-partials
#pragma unroll
    for (int nt = 0; nt < 5; nt++)
#pragma unroll
      for (int q = 0; q < 4; q++)
        acc[nt][q] = accs[0][l][nt * 4 + q] + accs[1][l][nt * 4 + q] +
                     accs[2][l][nt * 4 + q] + accs[3][l][nt * 4 + q];

    // epilogue: +b1, LN(72), GELU, @w2.T + b2
    float yv[5][4];
    float sum[4] = {0.f, 0.f, 0.f, 0.f}, sum2[4] = {0.f, 0.f, 0.f, 0.f};
#pragma unroll
    for (int nt = 0; nt < 5; nt++) {
      int j = 16 * nt + n16;
      bool val = (j < 72);
#pragma unroll
      for (int q = 0; q < 4; q++) {
        float v = val ? (acc[nt][q] + b1s[j]) : 0.f;
        yv[nt][q] = v;
        sum[q] += v; sum2[q] = fmaf(v, v, sum2[q]);
      }
    }
#pragma unroll
    for (int m = 1; m < 16; m <<= 1) {
#pragma unroll
      for (int q = 0; q < 4; q++) {
        sum[q] += __shfl_xor(sum[q], m, 64);
        sum2[q] += __shfl_xor(sum2[q], m, 64);
      }
    }
    float mm[4], rs[4];
#pragma unroll
    for (int q = 0; q < 4; q++) {
      mm[q] = sum[q] * (1.f / 72.f);
      rs[q] = rsqrtf(sum2[q] * (1.f / 72.f) - mm[q] * mm[q] + EPS_);
    }

    float p[4][12];
#pragma unroll
    for (int q = 0; q < 4; q++)
#pragma unroll
      for (int c = 0; c < 12; c++) p[q][c] = 0.f;

#pragma unroll
    for (int nt = 0; nt < 5; nt++) {
      int j = 16 * nt + n16;
      if (j < 72) {
        float lw = lnws[j], lb = lnbs[j];
#pragma unroll
        for (int q = 0; q < 4; q++) {
          float y2 = gelu_f((yv[nt][q] - mm[q]) * rs[q] * lw + lb);
#pragma unroll
          for (int c = 0; c < 12; c++) p[q][c] = fmaf(y2, w2s[c][j], p[q][c]);
        }
      }
    }
#pragma unroll
    for (int m = 1; m < 16; m <<= 1) {
#pragma unroll
      for (int q = 0; q < 4; q++)
#pragma unroll
        for (int c = 0; c < 12; c++) p[q][c] += __shfl_xor(p[q][c], m, 64);
    }

    if (n16 == 0) {
#pragma unroll
      for (int q = 0; q < 4; q++) {
        int m = m0 + 4 * g + q;
        float4 o0 = make_float4(p[q][0] + a.b2[0], p[q][1] + a.b2[1], p[q][2] + a.b2[2], p[q][3] + a.b2[3]);
        float4 o1 = make_float4(p[q][4] + a.b2[4], p[q][5] + a.b2[5], p[q][6] + a.b2[6], p[q][7] + a.b2[7]);
        float4 o2 = make_float4(p[q][8] + a.b2[8], p[q][9] + a.b2[9], p[q][10] + a.b2[10], p[q][11] + a.b2[11]);
        *(float4*)&a.out[(size_t)m * 12]     = o0;
        *(float4*)&a.out[(size_t)m * 12 + 4] = o1;
        *(float4*)&a.out[(size_t)m * 12 + 8] = o2;
      }
    }
  }
}

// ---------------- launch ----------------
extern "C" void kernel_launch(void* const* d_in, const int* in_sizes, int n_in,
                              void* d_out, int out_size, void* d_ws, size_t ws_size,
                              hipStream_t stream) {
  const float* x = (const float*)d_in[0];

  _Float16* tabT = (_Float16*)d_ws;                              // 450*1024*2 = 921600 B
  _Float16* wf  = (_Float16*)((char*)d_ws + 921600);             // 65536 B
  _Float16* pwf = (_Float16*)((char*)d_ws + 987136);             // 59392 B
  __hip_bfloat16* w1b = (__hip_bfloat16*)((char*)d_ws + 1046528); // 1036800 B -> ends 2083328
  char* rec = (char*)d_ws + (size_t)(2 * 1024 * 1024);           // 8192 * 14400 B

  k_table<<<1800, 256, 0, stream>>>(tabT);
  k_prep<<<2269, 256, 0, stream>>>((const float*)d_in[11], (const float*)d_in[21],
                                   (const float*)d_in[13], (const float*)d_in[23],
                                   (const float*)d_in[25], wf, pwf, w1b);
  k_dft<<<2048, 256, 0, stream>>>(x, tabT, (float*)rec);

  NetArgs na;
  na.ccw = (const float*)d_in[1];
  na.ccb = (const float*)d_in[2];
  na.cclnw = (const float*)d_in[3];
  na.cclnb = (const float*)d_in[4];
  for (int e = 0; e < 2; e++) {
    int o = 5 + e * 10;
    na.l1w[e] = (const float*)d_in[o + 0];
    na.l1b[e] = (const float*)d_in[o + 1];
    na.l2w[e] = (const float*)d_in[o + 2];
    na.l2b[e] = (const float*)d_in[o + 3];
    na.l3w[e] = (const float*)d_in[o + 4];
    na.l3b[e] = (const float*)d_in[o + 5];
    na.cb[e]  = (const float*)d_in[o + 7];
    na.pb[e]  = (const float*)d_in[o + 9];
  }
  na.wf = wf;
  na.pwf = pwf;
  na.rec = rec;
  k_net<<<8192, 256, 0, stream>>>(na);

  MlpArgs ma;
  ma.rec = rec;
  ma.w1b = w1b;
  ma.b1 = (const float*)d_in[26];
  ma.lnw = (const float*)d_in[27];
  ma.lnb = (const float*)d_in[28];
  ma.w2 = (const float*)d_in[29];
  ma.b2 = (const float*)d_in[30];
  ma.out = (float*)d_out;
  k_mlp<<<512, 256, 0, stream>>>(ma);
}